// Round 4
// baseline (953.418 us; speedup 1.0000x reference)
//
#include <hip/hip_runtime.h>
#include <math.h>

#define NH 128          // hidden size
#define NI 6            // input size
#define SIGMA_REC 0.15f
#define WARM 384        // warmup steps (R16/R17: absmax at 384 == f16 floor)
#define NCHB 64         // chunks per batch-group: grid = (B/32) x 64 = 256
                        // blocks (1 wave/CU); path = WARM + 47 = 431 steps.
#define TILE_T 4        // transpose kernel time-tile
#define RDEPTH 7        // prefetch depth in steps (ring has 8 slots; depth 7
                        // so refill slot != just-read slot -> no LDS race)

typedef __fp16 h2v __attribute__((ext_vector_type(2)));
typedef unsigned int vu4 __attribute__((ext_vector_type(4)));
typedef __fp16 f16x8 __attribute__((ext_vector_type(8)));
typedef float f32x16 __attribute__((ext_vector_type(16)));

__device__ __forceinline__ unsigned int pkh(float a, float b) {
    h2v h = __builtin_amdgcn_cvt_pkrtz(a, b);   // pack 2 f32 -> 2 f16 (RTZ)
    return __builtin_bit_cast(unsigned int, h);
}
#define H2(u) __builtin_bit_cast(h2v, (unsigned int)(u))

struct U6 { float2 a, b, c; };

// async 16B/lane global -> LDS (wave-uniform LDS base + lane*16)
__device__ __forceinline__ void gll16(const void* g, void* l) {
    __builtin_amdgcn_global_load_lds(
        (const __attribute__((address_space(1))) unsigned int*)g,
        (__attribute__((address_space(3))) unsigned int*)l, 16, 0, 0);
}

// fallback-kernel helpers (R12-proven)
#define DOT_OCT(j, xv) \
    c00 = __builtin_amdgcn_fdot2(H2(a##j.x), H2((xv).x), c00, false); \
    c01 = __builtin_amdgcn_fdot2(H2(a##j.y), H2((xv).y), c01, false); \
    c02 = __builtin_amdgcn_fdot2(H2(a##j.z), H2((xv).z), c02, false); \
    c03 = __builtin_amdgcn_fdot2(H2(a##j.w), H2((xv).w), c03, false); \
    c10 = __builtin_amdgcn_fdot2(H2(b##j.x), H2((xv).x), c10, false); \
    c11 = __builtin_amdgcn_fdot2(H2(b##j.y), H2((xv).y), c11, false); \
    c12 = __builtin_amdgcn_fdot2(H2(b##j.z), H2((xv).z), c12, false); \
    c13 = __builtin_amdgcn_fdot2(H2(b##j.w), H2((xv).w), c13, false)

#define LDW(j) vu4 a##j, b##j; { \
    const float4* q0 = reinterpret_cast<const float4*>(wr0 + 8 * (j)); \
    const float4* q1 = reinterpret_cast<const float4*>(wr1 + 8 * (j)); \
    float4 f0 = q0[0], f1 = q0[1], g0 = q1[0], g1 = q1[1]; \
    a##j = (vu4){pkh(f0.x, f0.y), pkh(f0.z, f0.w), pkh(f1.x, f1.y), pkh(f1.z, f1.w)}; \
    b##j = (vu4){pkh(g0.x, g0.y), pkh(g0.z, g0.w), pkh(g1.x, g1.y), pkh(g1.z, g1.w)}; }

#define PIN_AB() \
    asm volatile("" : "+v"(a0), "+v"(a1), "+v"(a2),  "+v"(a3), \
                      "+v"(a4), "+v"(a5), "+v"(a6),  "+v"(a7), \
                      "+v"(a8), "+v"(a9), "+v"(a10), "+v"(a11), \
                      "+v"(a12), "+v"(a13), "+v"(a14), "+v"(a15)); \
    asm volatile("" : "+v"(b0), "+v"(b1), "+v"(b2),  "+v"(b3), \
                      "+v"(b4), "+v"(b5), "+v"(b6),  "+v"(b7), \
                      "+v"(b8), "+v"(b9), "+v"(b10), "+v"(b11), \
                      "+v"(b12), "+v"(b13), "+v"(b14), "+v"(b15))

// ---------------------------------------------------------------------------
// Kernel 0: precompute drive d[b,t,n] = u.W_in + scale*nz + p, packed f16.
// (UNCHANGED — layout dpre[b][t][dword j] = pkh(d(2j), d(2j+1)).)
// ---------------------------------------------------------------------------
__global__ __launch_bounds__(256) void drive_kernel(
    const float* __restrict__ u,      // [B,T,6]
    const float* __restrict__ p,      // [B,128]
    const float* __restrict__ alpha,  // [1]
    const float* __restrict__ noise,  // [B,T,128]
    const float* __restrict__ W_in,   // [128,6]
    unsigned int* __restrict__ dpre,  // [B*T*64]
    int B, int T)
{
    const float av    = alpha[0];
    const float scale = sqrtf(2.0f * av * SIGMA_REC * SIGMA_REC);
    const size_t total = (size_t)B * T * 64;
    for (size_t idx = (size_t)blockIdx.x * 256 + threadIdx.x; idx < total;
         idx += (size_t)gridDim.x * 256) {
        const int    l  = (int)(idx & 63);
        const size_t bt = idx >> 6;
        const int    b  = (int)(bt / (unsigned)T);
        const int    t  = (int)(bt - (size_t)b * T);

        float2 nz = *reinterpret_cast<const float2*>(
            noise + ((size_t)b * T + t) * NH + 2 * l);
        const float2* ur = reinterpret_cast<const float2*>(
            u + ((size_t)b * T + t) * NI);
        float2 ua = ur[0], ub = ur[1], uc = ur[2];
        const float4* wv = reinterpret_cast<const float4*>(W_in + 2 * l * NI);
        float4 w0 = wv[0], w1 = wv[1], w2 = wv[2];   // rows 2l, 2l+1 (12 floats)
        float2 pv = *reinterpret_cast<const float2*>(p + (size_t)b * NH + 2 * l);

        float dx = fmaf(ua.x, w0.x, fmaf(ua.y, w0.y, fmaf(ub.x, w0.z,
                   fmaf(ub.y, w0.w, fmaf(uc.x, w1.x, fmaf(uc.y, w1.y,
                   fmaf(scale, nz.x, pv.x)))))));
        float dy = fmaf(ua.x, w1.z, fmaf(ua.y, w1.w, fmaf(ub.x, w2.x,
                   fmaf(ub.y, w2.y, fmaf(uc.x, w2.z, fmaf(uc.y, w2.w,
                   fmaf(scale, nz.y, pv.y)))))));
        dpre[idx] = pkh(dx, dy);
    }
}

// ---------------------------------------------------------------------------
// R20: transpose dpre -> dpre2, the scan's exact consumption order.
// dpre2 dword addr = ((bg*T + t)*2048) + k*256 + lane*4 + m, holding
// dpre[32bg + (lane&31)][t][j] with j = mt*16 + g*4 + 2*(lane>>5) + r,
// q = mt*4+g = 2k + (m>>1), r = m&1. (UNCHANGED from R20.)
// ---------------------------------------------------------------------------
__global__ __launch_bounds__(256) void transpose_d(
    const unsigned int* __restrict__ dpre,   // [B,T,64]
    unsigned int* __restrict__ dpre2,        // [B/32, T, 2048]
    int T)
{
    __shared__ unsigned int lds[256 * 33];   // [(tt*64+j)*33 + col]
    const int tid = threadIdx.x;
    const int t0  = blockIdx.x * TILE_T;
    const int bg  = blockIdx.y;
    const int nt  = min(TILE_T, T - t0);
    if (nt <= 0) return;

    // phase 1: read 32 batches x nt*64 dwords (8 threads per batch row)
    const int bi = tid >> 3;      // batch within group, 0..31
    const int si = tid & 7;
    const unsigned int* src =
        dpre + ((size_t)(bg * 32 + bi) * T + t0) * 64;
#pragma unroll
    for (int c = 0; c < 8; ++c) {
        const int l = 32 * c + 4 * si;           // dword offset in [0,256)
        if (l < nt * 64) {
            uint4 v = *reinterpret_cast<const uint4*>(src + l);
            lds[(l + 0) * 33 + bi] = v.x;
            lds[(l + 1) * 33 + bi] = v.y;
            lds[(l + 2) * 33 + bi] = v.z;
            lds[(l + 3) * 33 + bi] = v.w;
        }
    }
    __syncthreads();

    // phase 2: write coalesced (4 KB contiguous per instruction)
    uint4* out4 = reinterpret_cast<uint4*>(dpre2) + ((size_t)bg * T + t0) * 512;
#pragma unroll
    for (int c = 0; c < 8; ++c) {
        const int idx  = c * 256 + tid;          // uint4 index in [0, nt*512)
        const int tt   = idx >> 9;
        if (tt >= nt) break;
        const int k    = (idx >> 6) & 7;
        const int lane = idx & 63;
        const int hi   = lane >> 5, col = lane & 31;
        unsigned int w[4];
#pragma unroll
        for (int e = 0; e < 4; ++e) {
            const int q  = 2 * k + (e >> 1), r = e & 1;
            const int mt = q >> 2, g = q & 3;
            const int j  = mt * 16 + g * 4 + 2 * hi + r;
            w[e] = lds[(tt * 64 + j) * 33 + col];
        }
        out4[idx] = make_uint4(w[0], w[1], w[2], w[3]);
    }
}

// ---------------------------------------------------------------------------
// R21: MFMA chunked speculative scan with an 8-slot LDS d-ring fed by
// global_load_lds and counted vmcnt. R20 post-mortem: register dbuf gives
// only ~1 step of prefetch slack (compiler waits drain the just-issued
// loads), so step time = loaded-system latency (~3K cyc). The ring keeps
// RDEPTH-1=6 steps of loads in flight across steps (s_waitcnt vmcnt(56)
// never drains to 0 in the loop) -> latency hidden, step ~= compute.
// Refill at step t targets slot (t+7)&7 (read at step t-1, long consumed)
// so the async LDS write can never race the ds_read of live data.
//   A = W tile  : lane holds W[32*mt + (l&31)][16*kk + 8*(l>>5) + 0..7]
//   B = x       : lane holds x[16*kk + 8*(l>>5) + 0..7][b = l&31]
//   C/D         : lane holds (n = 32*mt + 8g + 4hi + 2r1 + delta, b = l&31)
// ---------------------------------------------------------------------------
__global__ __attribute__((amdgpu_flat_work_group_size(64, 64),
                          amdgpu_waves_per_eu(1, 1)))
void rnn_scan_mfma_t(
    const float* __restrict__ W_rec,         // [128,128]
    const unsigned int* __restrict__ dpre2,  // [B/32, T, 2048]
    float* __restrict__ states,              // [B,T,128]
    const float* __restrict__ alpha,         // [1]
    int T)
{
    const int bg    = blockIdx.x;        // batch group (32 rows)
    const int chunk = blockIdx.y;
    const int lane  = threadIdx.x;
    const int col   = lane & 31;         // batch within group
    const int hi    = lane >> 5;
    const int b     = bg * 32 + col;

    const int NS   = T - 1;                     // 2999 steps
    const int S    = (NS + NCHB - 1) / NCHB;    // 47
    const int s0   = chunk * S;
    if (s0 >= NS) return;
    const int e0   = min(NS, s0 + S);
    const int ws   = max(0, s0 - WARM);
    const int NSm1 = NS - 1;

    __shared__ uint4 ring[8][512];   // 64 KB: [slot][k*64 + lane]

    // ---- W fragments: Wf[mt][kk] covers W[32mt + col][16kk + 8hi .. +7] ----
    f16x8 Wf[4][8];
#pragma unroll
    for (int mt = 0; mt < 4; ++mt) {
        const float* wrow = W_rec + (size_t)(32 * mt + col) * NH + 8 * hi;
#pragma unroll
        for (int kk = 0; kk < 8; ++kk) {
            const float4* q = reinterpret_cast<const float4*>(wrow + 16 * kk);
            float4 f0 = q[0], f1 = q[1];
            vu4 uw = {pkh(f0.x, f0.y), pkh(f0.z, f0.w),
                      pkh(f1.x, f1.y), pkh(f1.z, f1.w)};
            Wf[mt][kk] = __builtin_bit_cast(f16x8, uw);
        }
    }
    // Pin to AGPRs (keeps 128 dwords off the arch-VGPR budget).
    asm volatile("" : "+a"(Wf[0][0]), "+a"(Wf[0][1]), "+a"(Wf[0][2]), "+a"(Wf[0][3]),
                      "+a"(Wf[0][4]), "+a"(Wf[0][5]), "+a"(Wf[0][6]), "+a"(Wf[0][7]),
                      "+a"(Wf[1][0]), "+a"(Wf[1][1]), "+a"(Wf[1][2]), "+a"(Wf[1][3]),
                      "+a"(Wf[1][4]), "+a"(Wf[1][5]), "+a"(Wf[1][6]), "+a"(Wf[1][7]));
    asm volatile("" : "+a"(Wf[2][0]), "+a"(Wf[2][1]), "+a"(Wf[2][2]), "+a"(Wf[2][3]),
                      "+a"(Wf[2][4]), "+a"(Wf[2][5]), "+a"(Wf[2][6]), "+a"(Wf[2][7]),
                      "+a"(Wf[3][0]), "+a"(Wf[3][1]), "+a"(Wf[3][2]), "+a"(Wf[3][3]),
                      "+a"(Wf[3][4]), "+a"(Wf[3][5]), "+a"(Wf[3][6]), "+a"(Wf[3][7]));

    const float av  = alpha[0];
    const float oma = 1.0f - av;
    f32x16 omv, avv, z16;
#pragma unroll
    for (int i = 0; i < 16; ++i) { omv[i] = oma; avv[i] = av; z16[i] = 0.f; }

    // per-lane global byte base of the coalesced d stream
    const char* d2base = (const char*)dpre2 + (size_t)bg * T * 8192 +
                         (size_t)lane * 16;
    float* st_b = states + (size_t)b * T * NH;

    f32x16 xsv[4];
#pragma unroll
    for (int mt = 0; mt < 4; ++mt) xsv[mt] = z16;
    unsigned Bfd[8][4];
#pragma unroll
    for (int kk = 0; kk < 8; ++kk)
#pragma unroll
        for (int j = 0; j < 4; ++j) Bfd[kk][j] = 0u;

    if (chunk == 0) {   // true t=0 state is zero; store it
        float4 z4 = make_float4(0.f, 0.f, 0.f, 0.f);
#pragma unroll
        for (int mt = 0; mt < 4; ++mt)
#pragma unroll
            for (int g = 0; g < 4; ++g)
                *reinterpret_cast<float4*>(st_b + 32 * mt + 8 * g + 4 * hi) = z4;
    }

    // issue one step's 8 async loads: data(td) -> slot (ts & 7)
    auto ISSUE = [&](int ts, int td) {
        const char* g = d2base + (size_t)td * 8192;
        uint4* dst = ring[ts & 7];
#pragma unroll
        for (int k = 0; k < 8; ++k)
            gll16(g + (size_t)k * 1024, dst + k * 64);
    };

    // prologue: fill RDEPTH=7 slots (56 loads in flight)
    for (int s = 0; s < RDEPTH; ++s) ISSUE(ws + s, min(ws + s, NSm1));

#pragma unroll 1
    for (int t = ws; t < e0; ++t) {
        // keep the pipe full: issue step t+7's loads before waiting
        ISSUE(t + RDEPTH, min(t + RDEPTH, NSm1));
        // wait only for slot t's 8 loads (56 newer ops stay in flight)
        asm volatile("s_waitcnt vmcnt(56)" ::: "memory");
        const uint4* sl = ring[t & 7];
        uint4 D[8];
#pragma unroll
        for (int k = 0; k < 8; ++k) D[k] = sl[k * 64 + lane];

        // C-init = drive d (f16 -> f32)
        f32x16 C[4];
#pragma unroll
        for (int k = 0; k < 8; ++k) {
            uint4 V = D[k];
            const int q0 = 2 * k, mt = q0 >> 2, g0 = q0 & 3, g1 = g0 + 1;
            h2v a0 = H2(V.x), a1 = H2(V.y), a2 = H2(V.z), a3 = H2(V.w);
            C[mt][4 * g0 + 0] = (float)a0.x;
            C[mt][4 * g0 + 1] = (float)a0.y;
            C[mt][4 * g0 + 2] = (float)a1.x;
            C[mt][4 * g0 + 3] = (float)a1.y;
            C[mt][4 * g1 + 0] = (float)a2.x;
            C[mt][4 * g1 + 1] = (float)a2.y;
            C[mt][4 * g1 + 2] = (float)a3.x;
            C[mt][4 * g1 + 3] = (float)a3.y;
        }

        // y = W*x + d : 4 independent accumulation chains
#pragma unroll
        for (int kk = 0; kk < 8; ++kk) {
            vu4 bu = {Bfd[kk][0], Bfd[kk][1], Bfd[kk][2], Bfd[kk][3]};
            f16x8 bb = __builtin_bit_cast(f16x8, bu);
#pragma unroll
            for (int mt = 0; mt < 4; ++mt)
                C[mt] = __builtin_amdgcn_mfma_f32_32x32x16_f16(
                    Wf[mt][kk], bb, C[mt], 0, 0, 0);
        }

        // blend: x = oma*x + av*relu(y)
#pragma unroll
        for (int mt = 0; mt < 4; ++mt) {
            f32x16 r = __builtin_elementwise_max(C[mt], z16);
            xsv[mt] = __builtin_elementwise_fma(omv, xsv[mt], avv * r);
        }

        if (t >= s0) {
            float* row = st_b + (size_t)(t + 1) * NH + 4 * hi;
#pragma unroll
            for (int mt = 0; mt < 4; ++mt)
#pragma unroll
                for (int g = 0; g < 4; ++g)
                    *reinterpret_cast<float4*>(row + 32 * mt + 8 * g) =
                        make_float4(xsv[mt][g * 4 + 0], xsv[mt][g * 4 + 1],
                                    xsv[mt][g * 4 + 2], xsv[mt][g * 4 + 3]);
        }

        // pack to f16 pairs; single-shuffle cross-half exchange -> B frags
        unsigned P[32];
#pragma unroll
        for (int i = 0; i < 32; ++i)
            P[i] = pkh(xsv[i >> 3][(2 * i) & 15], xsv[i >> 3][(2 * i + 1) & 15]);
#pragma unroll
        for (int mt = 0; mt < 4; ++mt) {
#pragma unroll
            for (int gp = 0; gp < 2; ++gp) {
#pragma unroll
                for (int r = 0; r < 2; ++r) {
                    unsigned u_ = P[mt * 8 + 4 * gp + r];
                    unsigned v_ = P[mt * 8 + 4 * gp + 2 + r];
                    unsigned m_ = hi ? u_ : v_;
                    unsigned sm_ = (unsigned)__shfl_xor((int)m_, 32);
                    Bfd[2 * mt + gp][r]     = hi ? sm_ : u_;
                    Bfd[2 * mt + gp][2 + r] = hi ? v_  : sm_;
                }
            }
        }
    }
}

// ---------------------------------------------------------------------------
// R19 scan kept verbatim: mid-size workspace fallback (ws >= 98 MB < 197 MB).
// ---------------------------------------------------------------------------
__global__ __attribute__((amdgpu_flat_work_group_size(64, 64),
                          amdgpu_waves_per_eu(1, 1)))
void rnn_scan_mfma(
    const float* __restrict__ W_rec,        // [128,128]
    const unsigned int* __restrict__ dpre,  // [B*T*64]
    float* __restrict__ states,             // [B,T,128]
    const float* __restrict__ alpha,        // [1]
    int T)
{
    const int bg    = blockIdx.x;
    const int chunk = blockIdx.y;
    const int lane  = threadIdx.x;
    const int col   = lane & 31;
    const int hi    = lane >> 5;
    const int b     = bg * 32 + col;

    const int NS   = T - 1;
    const int S    = (NS + NCHB - 1) / NCHB;
    const int s0   = chunk * S;
    if (s0 >= NS) return;
    const int e0   = min(NS, s0 + S);
    const int ws   = max(0, s0 - WARM);
    const int NSm1 = NS - 1;

    f16x8 Wf[4][8];
#pragma unroll
    for (int mt = 0; mt < 4; ++mt) {
        const float* wrow = W_rec + (size_t)(32 * mt + col) * NH + 8 * hi;
#pragma unroll
        for (int kk = 0; kk < 8; ++kk) {
            const float4* q = reinterpret_cast<const float4*>(wrow + 16 * kk);
            float4 f0 = q[0], f1 = q[1];
            vu4 uw = {pkh(f0.x, f0.y), pkh(f0.z, f0.w),
                      pkh(f1.x, f1.y), pkh(f1.z, f1.w)};
            Wf[mt][kk] = __builtin_bit_cast(f16x8, uw);
        }
    }
    asm volatile("" : "+a"(Wf[0][0]), "+a"(Wf[0][1]), "+a"(Wf[0][2]), "+a"(Wf[0][3]),
                      "+a"(Wf[0][4]), "+a"(Wf[0][5]), "+a"(Wf[0][6]), "+a"(Wf[0][7]),
                      "+a"(Wf[1][0]), "+a"(Wf[1][1]), "+a"(Wf[1][2]), "+a"(Wf[1][3]),
                      "+a"(Wf[1][4]), "+a"(Wf[1][5]), "+a"(Wf[1][6]), "+a"(Wf[1][7]));
    asm volatile("" : "+a"(Wf[2][0]), "+a"(Wf[2][1]), "+a"(Wf[2][2]), "+a"(Wf[2][3]),
                      "+a"(Wf[2][4]), "+a"(Wf[2][5]), "+a"(Wf[2][6]), "+a"(Wf[2][7]),
                      "+a"(Wf[3][0]), "+a"(Wf[3][1]), "+a"(Wf[3][2]), "+a"(Wf[3][3]),
                      "+a"(Wf[3][4]), "+a"(Wf[3][5]), "+a"(Wf[3][6]), "+a"(Wf[3][7]));

    const float av  = alpha[0];
    const float oma = 1.0f - av;
    f32x16 omv, avv, z16;
#pragma unroll
    for (int i = 0; i < 16; ++i) { omv[i] = oma; avv[i] = av; z16[i] = 0.f; }

    const unsigned int* dp_b = dpre + (size_t)b * T * 64;
    float* st_b = states + (size_t)b * T * NH;

    f32x16 xsv[4];
#pragma unroll
    for (int mt = 0; mt < 4; ++mt) xsv[mt] = z16;
    unsigned Bfd[8][4];
#pragma unroll
    for (int kk = 0; kk < 8; ++kk)
#pragma unroll
        for (int j = 0; j < 4; ++j) Bfd[kk][j] = 0u;

    if (chunk == 0) {
        float4 z4 = make_float4(0.f, 0.f, 0.f, 0.f);
#pragma unroll
        for (int mt = 0; mt < 4; ++mt)
#pragma unroll
            for (int g = 0; g < 4; ++g)
                *reinterpret_cast<float4*>(st_b + 32 * mt + 8 * g + 4 * hi) = z4;
    }

    uint2 dA[16];
#define LDDM(BUF, tt) { \
    const unsigned int* rp_ = dp_b + (size_t)(tt) * 64 + 2 * hi; \
    _Pragma("unroll") \
    for (int mt_ = 0; mt_ < 4; ++mt_) { \
        _Pragma("unroll") \
        for (int g_ = 0; g_ < 4; ++g_) \
            BUF[mt_ * 4 + g_] = \
                *reinterpret_cast<const uint2*>(rp_ + mt_ * 16 + g_ * 4); \
    } }

    LDDM(dA, ws)

#define STEPM(tt) { \
    f32x16 C[4]; \
    _Pragma("unroll") \
    for (int mt_ = 0; mt_ < 4; ++mt_) { \
        _Pragma("unroll") \
        for (int g_ = 0; g_ < 4; ++g_) { \
            uint2 dw_ = dA[mt_ * 4 + g_]; \
            h2v dl_ = H2(dw_.x), dh_ = H2(dw_.y); \
            C[mt_][4 * g_ + 0] = (float)dl_.x; \
            C[mt_][4 * g_ + 1] = (float)dl_.y; \
            C[mt_][4 * g_ + 2] = (float)dh_.x; \
            C[mt_][4 * g_ + 3] = (float)dh_.y; \
        } \
    } \
    LDDM(dA, min((tt) + 1, NSm1)) \
    _Pragma("unroll") \
    for (int kk_ = 0; kk_ < 8; ++kk_) { \
        vu4 bu_ = {Bfd[kk_][0], Bfd[kk_][1], Bfd[kk_][2], Bfd[kk_][3]}; \
        f16x8 bb_ = __builtin_bit_cast(f16x8, bu_); \
        _Pragma("unroll") \
        for (int mt_ = 0; mt_ < 4; ++mt_) \
            C[mt_] = __builtin_amdgcn_mfma_f32_32x32x16_f16( \
                Wf[mt_][kk_], bb_, C[mt_], 0, 0, 0); \
    } \
    _Pragma("unroll") \
    for (int mt_ = 0; mt_ < 4; ++mt_) { \
        f32x16 r_ = __builtin_elementwise_max(C[mt_], z16); \
        xsv[mt_] = __builtin_elementwise_fma(omv, xsv[mt_], avv * r_); \
    } \
    if ((tt) >= s0) { \
        float* row_ = st_b + (size_t)((tt) + 1) * NH + 4 * hi; \
        _Pragma("unroll") \
        for (int mt_ = 0; mt_ < 4; ++mt_) { \
            _Pragma("unroll") \
            for (int g_ = 0; g_ < 4; ++g_) \
                *reinterpret_cast<float4*>(row_ + 32 * mt_ + 8 * g_) = \
                    make_float4(xsv[mt_][g_ * 4 + 0], \
                                xsv[mt_][g_ * 4 + 1], \
                                xsv[mt_][g_ * 4 + 2], \
                                xsv[mt_][g_ * 4 + 3]); \
        } \
    } \
    unsigned P_[32]; \
    _Pragma("unroll") \
    for (int i_ = 0; i_ < 32; ++i_) \
        P_[i_] = pkh(xsv[i_ >> 3][(2 * i_) & 15], xsv[i_ >> 3][(2 * i_ + 1) & 15]); \
    _Pragma("unroll") \
    for (int mt_ = 0; mt_ < 4; ++mt_) { \
        _Pragma("unroll") \
        for (int gp_ = 0; gp_ < 2; ++gp_) { \
            _Pragma("unroll") \
            for (int r_ = 0; r_ < 2; ++r_) { \
                unsigned u_ = P_[mt_ * 8 + 4 * gp_ + r_]; \
                unsigned v_ = P_[mt_ * 8 + 4 * gp_ + 2 + r_]; \
                unsigned m_ = hi ? u_ : v_; \
                unsigned sm_ = (unsigned)__shfl_xor((int)m_, 32); \
                Bfd[2 * mt_ + gp_][r_]     = hi ? sm_ : u_; \
                Bfd[2 * mt_ + gp_][2 + r_] = hi ? v_  : sm_; \
            } \
        } \
    } }

#pragma unroll 1
    for (int t = ws; t < e0; ++t) {
        STEPM(t)
    }
#undef STEPM
#undef LDDM
}

// ---------------------------------------------------------------------------
// Fallback scan (R12 verbatim, exact, non-chunked): if ws_size too small.
// ---------------------------------------------------------------------------
__global__ __attribute__((amdgpu_flat_work_group_size(64, 64),
                          amdgpu_waves_per_eu(1, 1)))
void rnn_scan_fb(
    const float* __restrict__ u, const float* __restrict__ p,
    const float* __restrict__ alpha, const float* __restrict__ noise,
    const float* __restrict__ W_rec, const float* __restrict__ W_in,
    float* __restrict__ states, int T)
{
    const int b    = blockIdx.x;
    const int lane = threadIdx.x;
    const int n0   = lane * 2;

    __shared__ unsigned int xsh[64];

    const float* wr0 = W_rec + (size_t)n0 * NH;
    const float* wr1 = wr0 + NH;
    LDW(0)  LDW(1)  LDW(2)  LDW(3)  LDW(4)  LDW(5)  LDW(6)  LDW(7)
    LDW(8)  LDW(9)  LDW(10) LDW(11) LDW(12) LDW(13) LDW(14) LDW(15)
    PIN_AB();

    const float wiA0 = W_in[n0 * NI + 0], wiA1 = W_in[n0 * NI + 1];
    const float wiA2 = W_in[n0 * NI + 2], wiA3 = W_in[n0 * NI + 3];
    const float wiA4 = W_in[n0 * NI + 4], wiA5 = W_in[n0 * NI + 5];
    const float wiB0 = W_in[(n0 + 1) * NI + 0], wiB1 = W_in[(n0 + 1) * NI + 1];
    const float wiB2 = W_in[(n0 + 1) * NI + 2], wiB3 = W_in[(n0 + 1) * NI + 3];
    const float wiB4 = W_in[(n0 + 1) * NI + 4], wiB5 = W_in[(n0 + 1) * NI + 5];

    const float2 pn   = *reinterpret_cast<const float2*>(p + (size_t)b * NH + n0);
    const float av    = alpha[0];
    const float oma   = 1.0f - av;
    const float scale = sqrtf(2.0f * av * SIGMA_REC * SIGMA_REC);

    const float* noise_b = noise + (size_t)b * T * NH + n0;
    unsigned int zv;
    asm volatile("v_mov_b32 %0, 0" : "=v"(zv));
    const float* u_b = u + (size_t)b * T * NI + zv;
    float* st_ptr = states + (size_t)b * T * NH + n0 + NH;

    xsh[lane] = 0u;
    *reinterpret_cast<float2*>(states + (size_t)b * T * NH + n0) = make_float2(0.f, 0.f);
    float xo0 = 0.0f, xo1 = 0.0f;

    auto LDnz = [&](int t) {
        return *reinterpret_cast<const float2*>(noise_b + (size_t)t * NH);
    };
    auto loadU = [&](int t) {
        const float2* up = reinterpret_cast<const float2*>(u_b + (size_t)t * NI);
        U6 r; r.a = up[0]; r.b = up[1]; r.c = up[2]; return r;
    };
    auto mkd = [&](float2 nz, const U6& uu) {
        float dx = fmaf(uu.a.x, wiA0, fmaf(uu.a.y, wiA1, fmaf(uu.b.x, wiA2,
                   fmaf(uu.b.y, wiA3, fmaf(uu.c.x, wiA4, fmaf(uu.c.y, wiA5,
                   fmaf(scale, nz.x, pn.x)))))));
        float dy = fmaf(uu.a.x, wiB0, fmaf(uu.a.y, wiB1, fmaf(uu.b.x, wiB2,
                   fmaf(uu.b.y, wiB3, fmaf(uu.c.x, wiB4, fmaf(uu.c.y, wiB5,
                   fmaf(scale, nz.y, pn.y)))))));
        return make_float2(dx, dy);
    };
    auto step = [&](float2 d) {
        const vu4* xr = reinterpret_cast<const vu4*>(xsh);
        float c00 = 0.f, c01 = 0.f, c02 = 0.f, c03 = 0.f;
        float c10 = 0.f, c11 = 0.f, c12 = 0.f, c13 = 0.f;
        vu4 xv0 = xr[0], xv1 = xr[1], xv2 = xr[2], xv3 = xr[3];
        vu4 xv4 = xr[4], xv5 = xr[5], xv6 = xr[6], xv7 = xr[7];
        DOT_OCT(0, xv0);  DOT_OCT(1, xv1);  DOT_OCT(2, xv2);  DOT_OCT(3, xv3);
        vu4 xv8 = xr[8], xv9 = xr[9], xv10 = xr[10], xv11 = xr[11];
        DOT_OCT(4, xv4);  DOT_OCT(5, xv5);  DOT_OCT(6, xv6);  DOT_OCT(7, xv7);
        vu4 xv12 = xr[12], xv13 = xr[13], xv14 = xr[14], xv15 = xr[15];
        DOT_OCT(8, xv8);  DOT_OCT(9, xv9);  DOT_OCT(10, xv10); DOT_OCT(11, xv11);
        DOT_OCT(12, xv12); DOT_OCT(13, xv13); DOT_OCT(14, xv14); DOT_OCT(15, xv15);
        float pre0 = ((c00 + c01) + (c02 + c03)) + d.x;
        float pre1 = ((c10 + c11) + (c12 + c13)) + d.y;
        float xn0 = fmaf(oma, xo0, av * fmaxf(pre0, 0.f));
        float xn1 = fmaf(oma, xo1, av * fmaxf(pre1, 0.f));
        xo0 = xn0; xo1 = xn1;
        *reinterpret_cast<float2*>(st_ptr) = make_float2(xn0, xn1);
        st_ptr += NH;
        xsh[lane] = pkh(xn0, xn1);
    };

    float2 nz0 = LDnz(0), nz1 = LDnz(1), nz2 = LDnz(2), nz3 = LDnz(3);
    U6 u0 = loadU(0), u1 = loadU(1), u2 = loadU(2), u3 = loadU(3);
    float2 nzA0 = LDnz(4), nzA1 = LDnz(5);   U6 uA0 = loadU(4), uA1 = loadU(5);
    float2 nzB0 = LDnz(6), nzB1 = LDnz(7);   U6 uB0 = loadU(6), uB1 = loadU(7);
    float2 d0 = mkd(nz0, u0), d1 = mkd(nz1, u1);
    float2 d2 = mkd(nz2, u2), d3 = mkd(nz3, u3);

    int t = 0;
    for (; t + 1 < T - 1; t += 2) {
        const int t8 = min(t + 8, T - 1), t9 = min(t + 9, T - 1);
        float2 nzC0 = LDnz(t8), nzC1 = LDnz(t9);
        U6 uC0 = loadU(t8), uC1 = loadU(t9);
        float2 dE = mkd(nzA0, uA0), dF = mkd(nzA1, uA1);
        step(d0);
        step(d1);
        d0 = d2; d1 = d3; d2 = dE; d3 = dF;
        nzA0 = nzB0; nzA1 = nzB1; uA0 = uB0; uA1 = uB1;
        nzB0 = nzC0; nzB1 = nzC1; uB0 = uC0; uB1 = uC1;
    }
    if (t < T - 1) step(d0);
}

// ---------------------------------------------------------------------------
// Projection: out[r,o] = sum_n relu(states[r,n]) * W_out[o,n]
// ---------------------------------------------------------------------------
__global__ __launch_bounds__(256) void out_proj_kernel(
    const float* __restrict__ states,  // [rows,128]
    const float* __restrict__ W_out,   // [2,128]
    float* __restrict__ out,           // [rows,2]
    int rows)
{
    const int wave = threadIdx.x >> 6;
    const int lane = threadIdx.x & 63;
    const int l    = lane & 31;
    const int row  = blockIdx.x * 8 + wave * 2 + (lane >> 5);
    if (row >= rows) return;

    float4 s = *reinterpret_cast<const float4*>(states + (size_t)row * NH + l * 4);
    s.x = fmaxf(s.x, 0.f); s.y = fmaxf(s.y, 0.f);
    s.z = fmaxf(s.z, 0.f); s.w = fmaxf(s.w, 0.f);
    float4 wa = reinterpret_cast<const float4*>(W_out)[l];
    float4 wb = reinterpret_cast<const float4*>(W_out + NH)[l];
    float c0 = s.x * wa.x + s.y * wa.y + s.z * wa.z + s.w * wa.w;
    float c1 = s.x * wb.x + s.y * wb.y + s.z * wb.z + s.w * wb.w;

#pragma unroll
    for (int off = 16; off >= 1; off >>= 1) {
        c0 += __shfl_xor(c0, off);
        c1 += __shfl_xor(c1, off);
    }
    if (l == 0) {
        *reinterpret_cast<float2*>(out + (size_t)row * 2) = make_float2(c0, c1);
    }
}

// ---------------------------------------------------------------------------
extern "C" void kernel_launch(void* const* d_in, const int* in_sizes, int n_in,
                              void* d_out, int out_size, void* d_ws, size_t ws_size,
                              hipStream_t stream) {
    const float* u     = (const float*)d_in[0];
    const float* p     = (const float*)d_in[1];
    const float* alpha = (const float*)d_in[2];
    const float* noise = (const float*)d_in[3];
    const float* W_rec = (const float*)d_in[4];
    const float* W_in  = (const float*)d_in[5];
    const float* W_out = (const float*)d_in[6];

    const int B = in_sizes[1] / NH;           // 128
    const int T = in_sizes[0] / (B * NI);     // 3000

    float* out    = (float*)d_out;                    // [B,T,2]
    float* states = out + (size_t)B * T * 2;          // [B,T,128]

    const size_t need1 = (size_t)B * T * 64 * sizeof(unsigned int);  // 98.3 MB
    if (d_ws != nullptr && ws_size >= 2 * need1 && (B % 32) == 0) {
        // full path: drive -> transpose -> LDS-ring MFMA scan
        unsigned int* dpre  = (unsigned int*)d_ws;
        unsigned int* dpre2 = (unsigned int*)((char*)d_ws + need1);
        drive_kernel<<<2048, 256, 0, stream>>>(u, p, alpha, noise, W_in,
                                               dpre, B, T);
        dim3 tgrid((T + TILE_T - 1) / TILE_T, B / 32);
        transpose_d<<<tgrid, 256, 0, stream>>>(dpre, dpre2, T);
        dim3 grid(B / 32, NCHB);
        rnn_scan_mfma_t<<<grid, 64, 0, stream>>>(W_rec, dpre2, states, alpha, T);
    } else if (d_ws != nullptr && ws_size >= need1 && (B % 32) == 0) {
        unsigned int* dpre = (unsigned int*)d_ws;
        drive_kernel<<<2048, 256, 0, stream>>>(u, p, alpha, noise, W_in,
                                               dpre, B, T);
        dim3 grid(B / 32, NCHB);
        rnn_scan_mfma<<<grid, 64, 0, stream>>>(W_rec, dpre, states, alpha, T);
    } else {
        rnn_scan_fb<<<B, 64, 0, stream>>>(u, p, alpha, noise, W_rec, W_in,
                                          states, T);
    }

    const int rows = B * T;
    out_proj_kernel<<<(rows + 7) / 8, 256, 0, stream>>>(states, W_out, out, rows);
}

// Round 5
// 859.507 us; speedup vs baseline: 1.1093x; 1.1093x over previous
//
#include <hip/hip_runtime.h>
#include <math.h>

#define NH 128          // hidden size
#define NI 6            // input size
#define SIGMA_REC 0.15f
#define WARM 384        // warmup steps (R16/R17: absmax at 384 == f16 floor)
#define NCHB 64         // chunks per batch-group: grid = (B/32) x 64 = 256
                        // blocks (1 block/CU); path = WARM + 47 = 431 steps.
#define TILE_T 4        // transpose kernel time-tile
#define NSLOT 12        // LDS ring slots (96 KB)

typedef __fp16 h2v __attribute__((ext_vector_type(2)));
typedef unsigned int vu4 __attribute__((ext_vector_type(4)));
typedef __fp16 f16x8 __attribute__((ext_vector_type(8)));
typedef float f32x16 __attribute__((ext_vector_type(16)));

__device__ __forceinline__ unsigned int pkh(float a, float b) {
    h2v h = __builtin_amdgcn_cvt_pkrtz(a, b);   // pack 2 f32 -> 2 f16 (RTZ)
    return __builtin_bit_cast(unsigned int, h);
}
#define H2(u) __builtin_bit_cast(h2v, (unsigned int)(u))

struct U6 { float2 a, b, c; };

// fallback-kernel helpers (R12-proven)
#define DOT_OCT(j, xv) \
    c00 = __builtin_amdgcn_fdot2(H2(a##j.x), H2((xv).x), c00, false); \
    c01 = __builtin_amdgcn_fdot2(H2(a##j.y), H2((xv).y), c01, false); \
    c02 = __builtin_amdgcn_fdot2(H2(a##j.z), H2((xv).z), c02, false); \
    c03 = __builtin_amdgcn_fdot2(H2(a##j.w), H2((xv).w), c03, false); \
    c10 = __builtin_amdgcn_fdot2(H2(b##j.x), H2((xv).x), c10, false); \
    c11 = __builtin_amdgcn_fdot2(H2(b##j.y), H2((xv).y), c11, false); \
    c12 = __builtin_amdgcn_fdot2(H2(b##j.z), H2((xv).z), c12, false); \
    c13 = __builtin_amdgcn_fdot2(H2(b##j.w), H2((xv).w), c13, false)

#define LDW(j) vu4 a##j, b##j; { \
    const float4* q0 = reinterpret_cast<const float4*>(wr0 + 8 * (j)); \
    const float4* q1 = reinterpret_cast<const float4*>(wr1 + 8 * (j)); \
    float4 f0 = q0[0], f1 = q0[1], g0 = q1[0], g1 = q1[1]; \
    a##j = (vu4){pkh(f0.x, f0.y), pkh(f0.z, f0.w), pkh(f1.x, f1.y), pkh(f1.z, f1.w)}; \
    b##j = (vu4){pkh(g0.x, g0.y), pkh(g0.z, g0.w), pkh(g1.x, g1.y), pkh(g1.z, g1.w)}; }

#define PIN_AB() \
    asm volatile("" : "+v"(a0), "+v"(a1), "+v"(a2),  "+v"(a3), \
                      "+v"(a4), "+v"(a5), "+v"(a6),  "+v"(a7), \
                      "+v"(a8), "+v"(a9), "+v"(a10), "+v"(a11), \
                      "+v"(a12), "+v"(a13), "+v"(a14), "+v"(a15)); \
    asm volatile("" : "+v"(b0), "+v"(b1), "+v"(b2),  "+v"(b3), \
                      "+v"(b4), "+v"(b5), "+v"(b6),  "+v"(b7), \
                      "+v"(b8), "+v"(b9), "+v"(b10), "+v"(b11), \
                      "+v"(b12), "+v"(b13), "+v"(b14), "+v"(b15))

// ---------------------------------------------------------------------------
// Kernel 0: precompute drive d[b,t,n] = u.W_in + scale*nz + p, packed f16.
// (UNCHANGED — layout dpre[b][t][dword j] = pkh(d(2j), d(2j+1)).)
// ---------------------------------------------------------------------------
__global__ __launch_bounds__(256) void drive_kernel(
    const float* __restrict__ u,      // [B,T,6]
    const float* __restrict__ p,      // [B,128]
    const float* __restrict__ alpha,  // [1]
    const float* __restrict__ noise,  // [B,T,128]
    const float* __restrict__ W_in,   // [128,6]
    unsigned int* __restrict__ dpre,  // [B*T*64]
    int B, int T)
{
    const float av    = alpha[0];
    const float scale = sqrtf(2.0f * av * SIGMA_REC * SIGMA_REC);
    const size_t total = (size_t)B * T * 64;
    for (size_t idx = (size_t)blockIdx.x * 256 + threadIdx.x; idx < total;
         idx += (size_t)gridDim.x * 256) {
        const int    l  = (int)(idx & 63);
        const size_t bt = idx >> 6;
        const int    b  = (int)(bt / (unsigned)T);
        const int    t  = (int)(bt - (size_t)b * T);

        float2 nz = *reinterpret_cast<const float2*>(
            noise + ((size_t)b * T + t) * NH + 2 * l);
        const float2* ur = reinterpret_cast<const float2*>(
            u + ((size_t)b * T + t) * NI);
        float2 ua = ur[0], ub = ur[1], uc = ur[2];
        const float4* wv = reinterpret_cast<const float4*>(W_in + 2 * l * NI);
        float4 w0 = wv[0], w1 = wv[1], w2 = wv[2];   // rows 2l, 2l+1 (12 floats)
        float2 pv = *reinterpret_cast<const float2*>(p + (size_t)b * NH + 2 * l);

        float dx = fmaf(ua.x, w0.x, fmaf(ua.y, w0.y, fmaf(ub.x, w0.z,
                   fmaf(ub.y, w0.w, fmaf(uc.x, w1.x, fmaf(uc.y, w1.y,
                   fmaf(scale, nz.x, pv.x)))))));
        float dy = fmaf(ua.x, w1.z, fmaf(ua.y, w1.w, fmaf(ub.x, w2.x,
                   fmaf(ub.y, w2.y, fmaf(uc.x, w2.z, fmaf(uc.y, w2.w,
                   fmaf(scale, nz.y, pv.y)))))));
        dpre[idx] = pkh(dx, dy);
    }
}

// ---------------------------------------------------------------------------
// R20: transpose dpre -> dpre2, the scan's exact consumption order.
// dpre2 dword addr = ((bg*T + t)*2048) + k*256 + lane*4 + m, holding
// dpre[32bg + (lane&31)][t][j] with j = mt*16 + g*4 + 2*(lane>>5) + r,
// q = mt*4+g = 2k + (m>>1), r = m&1. (UNCHANGED from R20.)
// ---------------------------------------------------------------------------
__global__ __launch_bounds__(256) void transpose_d(
    const unsigned int* __restrict__ dpre,   // [B,T,64]
    unsigned int* __restrict__ dpre2,        // [B/32, T, 2048]
    int T)
{
    __shared__ unsigned int lds[256 * 33];   // [(tt*64+j)*33 + col]
    const int tid = threadIdx.x;
    const int t0  = blockIdx.x * TILE_T;
    const int bg  = blockIdx.y;
    const int nt  = min(TILE_T, T - t0);
    if (nt <= 0) return;

    // phase 1: read 32 batches x nt*64 dwords (8 threads per batch row)
    const int bi = tid >> 3;      // batch within group, 0..31
    const int si = tid & 7;
    const unsigned int* src =
        dpre + ((size_t)(bg * 32 + bi) * T + t0) * 64;
#pragma unroll
    for (int c = 0; c < 8; ++c) {
        const int l = 32 * c + 4 * si;           // dword offset in [0,256)
        if (l < nt * 64) {
            uint4 v = *reinterpret_cast<const uint4*>(src + l);
            lds[(l + 0) * 33 + bi] = v.x;
            lds[(l + 1) * 33 + bi] = v.y;
            lds[(l + 2) * 33 + bi] = v.z;
            lds[(l + 3) * 33 + bi] = v.w;
        }
    }
    __syncthreads();

    // phase 2: write coalesced (4 KB contiguous per instruction)
    uint4* out4 = reinterpret_cast<uint4*>(dpre2) + ((size_t)bg * T + t0) * 512;
#pragma unroll
    for (int c = 0; c < 8; ++c) {
        const int idx  = c * 256 + tid;          // uint4 index in [0, nt*512)
        const int tt   = idx >> 9;
        if (tt >= nt) break;
        const int k    = (idx >> 6) & 7;
        const int lane = idx & 63;
        const int hi   = lane >> 5, col = lane & 31;
        unsigned int w[4];
#pragma unroll
        for (int e = 0; e < 4; ++e) {
            const int q  = 2 * k + (e >> 1), r = e & 1;
            const int mt = q >> 2, g = q & 3;
            const int j  = mt * 16 + g * 4 + 2 * hi + r;
            w[e] = lds[(tt * 64 + j) * 33 + col];
        }
        out4[idx] = make_uint4(w[0], w[1], w[2], w[3]);
    }
}

// ---------------------------------------------------------------------------
// R22: producer-consumer MFMA scan. Block = 4 waves on one CU.
//   wave 0            : the scan (unchanged math; reads d from LDS ring)
//   waves 1..3 (p=0..2): stream step rel = p, p+3, ... of the d-window
//     global -> regs (2-deep pipeline) -> ds_write ring[rel % 12].
// Sync: monotonic LDS counters via __hip_atomic (workgroup scope). The
// consumer's only waits are lgkmcnt on its own ds_read; ALL vmcnt stalls
// live in producer waves that run up to 11 steps ahead and overlap 3x.
// R19-R21 post-mortem: every single-wave prefetch form collapsed to ~2.3
// B/cyc effective d-throughput (compiler wait placement / per-wave MLP);
// wave specialization moves the stall off the serial wave entirely.
//   A = W tile  : lane holds W[32*mt + (l&31)][16*kk + 8*(l>>5) + 0..7]
//   B = x       : lane holds x[16*kk + 8*(l>>5) + 0..7][b = l&31]
//   C/D         : lane holds (n = 32*mt + 8g + 4hi + 2r1 + delta, b = l&31)
// ---------------------------------------------------------------------------
__global__ __attribute__((amdgpu_flat_work_group_size(256, 256),
                          amdgpu_waves_per_eu(1, 1)))
void rnn_scan_mfma_pc(
    const float* __restrict__ W_rec,         // [128,128]
    const unsigned int* __restrict__ dpre2,  // [B/32, T, 2048]
    float* __restrict__ states,              // [B,T,128]
    const float* __restrict__ alpha,         // [1]
    int T)
{
    const int bg    = blockIdx.x;        // batch group (32 rows)
    const int chunk = blockIdx.y;
    const int tid   = threadIdx.x;
    const int wv    = tid >> 6;          // 0 = consumer, 1..3 = producers
    const int lane  = tid & 63;
    const int col   = lane & 31;         // batch within group
    const int hi    = lane >> 5;
    const int b     = bg * 32 + col;

    const int NS   = T - 1;                     // 2999 steps
    const int S    = (NS + NCHB - 1) / NCHB;    // 47
    const int s0   = chunk * S;
    if (s0 >= NS) return;
    const int e0   = min(NS, s0 + S);
    const int ws   = max(0, s0 - WARM);
    const int L    = e0 - ws;                   // steps this block executes
    const int NSm1 = NS - 1;

    __shared__ uint4 ring[NSLOT][512];   // 96 KB: [slot][k*64 + lane]
    __shared__ int prod_c[3];            // last rel produced by producer p
    __shared__ int cons_c;               // last rel consumed

    if (tid == 0) { prod_c[0] = prod_c[1] = prod_c[2] = -1; cons_c = -1; }
    __syncthreads();   // once, before the loops — no barriers inside

    if (wv != 0) {
        // ---------------- producer wave (p = wv-1) ----------------
        const int p = wv - 1;
        const char* gb = (const char*)dpre2 + (size_t)bg * T * 8192 +
                         (size_t)lane * 16;
        if (p < L) {
            uint4 rA[8];
            {
                const char* g = gb + (size_t)min(ws + p, NSm1) * 8192;
#pragma unroll
                for (int k = 0; k < 8; ++k)
                    rA[k] = *reinterpret_cast<const uint4*>(g + (size_t)k * 1024);
            }
            int slot = p;
            for (int rel = p; rel < L; rel += 3) {
                const int reln = rel + 3;
                uint4 rB[8];
                if (reln < L) {
                    const char* g = gb + (size_t)min(ws + reln, NSm1) * 8192;
#pragma unroll
                    for (int k = 0; k < 8; ++k)
                        rB[k] = *reinterpret_cast<const uint4*>(g + (size_t)k * 1024);
                }
                // ring-space: slot holds rel-12; need cons >= rel-11 (margin 1)
                while (__hip_atomic_load(&cons_c, __ATOMIC_ACQUIRE,
                                         __HIP_MEMORY_SCOPE_WORKGROUP) < rel - 11) {}
                uint4* dst = ring[slot];
#pragma unroll
                for (int k = 0; k < 8; ++k) dst[k * 64 + lane] = rA[k];
                __hip_atomic_store(&prod_c[p], rel, __ATOMIC_RELEASE,
                                   __HIP_MEMORY_SCOPE_WORKGROUP);
#pragma unroll
                for (int k = 0; k < 8; ++k) rA[k] = rB[k];
                slot += 3; if (slot >= NSLOT) slot -= NSLOT;
            }
        }
        return;
    }

    // ---------------- consumer wave: the scan ----------------
    // W fragments: Wf[mt][kk] covers W[32mt + col][16kk + 8hi .. +7]
    f16x8 Wf[4][8];
#pragma unroll
    for (int mt = 0; mt < 4; ++mt) {
        const float* wrow = W_rec + (size_t)(32 * mt + col) * NH + 8 * hi;
#pragma unroll
        for (int kk = 0; kk < 8; ++kk) {
            const float4* q = reinterpret_cast<const float4*>(wrow + 16 * kk);
            float4 f0 = q[0], f1 = q[1];
            vu4 uw = {pkh(f0.x, f0.y), pkh(f0.z, f0.w),
                      pkh(f1.x, f1.y), pkh(f1.z, f1.w)};
            Wf[mt][kk] = __builtin_bit_cast(f16x8, uw);
        }
    }
    // Pin to AGPRs (keeps 128 dwords off the arch-VGPR budget).
    asm volatile("" : "+a"(Wf[0][0]), "+a"(Wf[0][1]), "+a"(Wf[0][2]), "+a"(Wf[0][3]),
                      "+a"(Wf[0][4]), "+a"(Wf[0][5]), "+a"(Wf[0][6]), "+a"(Wf[0][7]),
                      "+a"(Wf[1][0]), "+a"(Wf[1][1]), "+a"(Wf[1][2]), "+a"(Wf[1][3]),
                      "+a"(Wf[1][4]), "+a"(Wf[1][5]), "+a"(Wf[1][6]), "+a"(Wf[1][7]));
    asm volatile("" : "+a"(Wf[2][0]), "+a"(Wf[2][1]), "+a"(Wf[2][2]), "+a"(Wf[2][3]),
                      "+a"(Wf[2][4]), "+a"(Wf[2][5]), "+a"(Wf[2][6]), "+a"(Wf[2][7]),
                      "+a"(Wf[3][0]), "+a"(Wf[3][1]), "+a"(Wf[3][2]), "+a"(Wf[3][3]),
                      "+a"(Wf[3][4]), "+a"(Wf[3][5]), "+a"(Wf[3][6]), "+a"(Wf[3][7]));

    const float av  = alpha[0];
    const float oma = 1.0f - av;
    f32x16 omv, avv, z16;
#pragma unroll
    for (int i = 0; i < 16; ++i) { omv[i] = oma; avv[i] = av; z16[i] = 0.f; }

    float* st_b = states + (size_t)b * T * NH;

    f32x16 xsv[4];
#pragma unroll
    for (int mt = 0; mt < 4; ++mt) xsv[mt] = z16;
    unsigned Bfd[8][4];
#pragma unroll
    for (int kk = 0; kk < 8; ++kk)
#pragma unroll
        for (int j = 0; j < 4; ++j) Bfd[kk][j] = 0u;

    if (chunk == 0) {   // true t=0 state is zero; store it
        float4 z4 = make_float4(0.f, 0.f, 0.f, 0.f);
#pragma unroll
        for (int mt = 0; mt < 4; ++mt)
#pragma unroll
            for (int g = 0; g < 4; ++g)
                *reinterpret_cast<float4*>(st_b + 32 * mt + 8 * g + 4 * hi) = z4;
    }

    int pp = 0, slot = 0;
    const int srel = s0 - ws;   // first rel whose state is committed
#pragma unroll 1
    for (int rel = 0; rel < L; ++rel) {
        // wait for slot data (monotonic counter; acquire orders the ds_read)
        while (__hip_atomic_load(&prod_c[pp], __ATOMIC_ACQUIRE,
                                 __HIP_MEMORY_SCOPE_WORKGROUP) < rel) {}
        const uint4* sl = ring[slot];
        uint4 D[8];
#pragma unroll
        for (int k = 0; k < 8; ++k) D[k] = sl[k * 64 + lane];

        // C-init = drive d (f16 -> f32)
        f32x16 C[4];
#pragma unroll
        for (int k = 0; k < 8; ++k) {
            uint4 V = D[k];
            const int q0 = 2 * k, mt = q0 >> 2, g0 = q0 & 3, g1 = g0 + 1;
            h2v a0 = H2(V.x), a1 = H2(V.y), a2 = H2(V.z), a3 = H2(V.w);
            C[mt][4 * g0 + 0] = (float)a0.x;
            C[mt][4 * g0 + 1] = (float)a0.y;
            C[mt][4 * g0 + 2] = (float)a1.x;
            C[mt][4 * g0 + 3] = (float)a1.y;
            C[mt][4 * g1 + 0] = (float)a2.x;
            C[mt][4 * g1 + 1] = (float)a2.y;
            C[mt][4 * g1 + 2] = (float)a3.x;
            C[mt][4 * g1 + 3] = (float)a3.y;
        }

        // y = W*x + d : 4 independent accumulation chains
#pragma unroll
        for (int kk = 0; kk < 8; ++kk) {
            vu4 bu = {Bfd[kk][0], Bfd[kk][1], Bfd[kk][2], Bfd[kk][3]};
            f16x8 bb = __builtin_bit_cast(f16x8, bu);
#pragma unroll
            for (int mt = 0; mt < 4; ++mt)
                C[mt] = __builtin_amdgcn_mfma_f32_32x32x16_f16(
                    Wf[mt][kk], bb, C[mt], 0, 0, 0);
        }

        // free the slot as early as possible (data fully in regs/acc now)
        __hip_atomic_store(&cons_c, rel, __ATOMIC_RELEASE,
                           __HIP_MEMORY_SCOPE_WORKGROUP);

        // blend: x = oma*x + av*relu(y)
#pragma unroll
        for (int mt = 0; mt < 4; ++mt) {
            f32x16 r = __builtin_elementwise_max(C[mt], z16);
            xsv[mt] = __builtin_elementwise_fma(omv, xsv[mt], avv * r);
        }

        if (rel >= srel) {
            float* row = st_b + (size_t)(ws + rel + 1) * NH + 4 * hi;
#pragma unroll
            for (int mt = 0; mt < 4; ++mt)
#pragma unroll
                for (int g = 0; g < 4; ++g)
                    *reinterpret_cast<float4*>(row + 32 * mt + 8 * g) =
                        make_float4(xsv[mt][g * 4 + 0], xsv[mt][g * 4 + 1],
                                    xsv[mt][g * 4 + 2], xsv[mt][g * 4 + 3]);
        }

        // pack to f16 pairs; single-shuffle cross-half exchange -> B frags
        unsigned P[32];
#pragma unroll
        for (int i = 0; i < 32; ++i)
            P[i] = pkh(xsv[i >> 3][(2 * i) & 15], xsv[i >> 3][(2 * i + 1) & 15]);
#pragma unroll
        for (int mt = 0; mt < 4; ++mt) {
#pragma unroll
            for (int gp = 0; gp < 2; ++gp) {
#pragma unroll
                for (int r = 0; r < 2; ++r) {
                    unsigned u_ = P[mt * 8 + 4 * gp + r];
                    unsigned v_ = P[mt * 8 + 4 * gp + 2 + r];
                    unsigned m_ = hi ? u_ : v_;
                    unsigned sm_ = (unsigned)__shfl_xor((int)m_, 32);
                    Bfd[2 * mt + gp][r]     = hi ? sm_ : u_;
                    Bfd[2 * mt + gp][2 + r] = hi ? v_  : sm_;
                }
            }
        }

        if (++pp == 3) pp = 0;
        if (++slot == NSLOT) slot = 0;
    }
}

// ---------------------------------------------------------------------------
// R19 scan kept verbatim: mid-size workspace fallback (ws >= 98 MB < 197 MB).
// ---------------------------------------------------------------------------
__global__ __attribute__((amdgpu_flat_work_group_size(64, 64),
                          amdgpu_waves_per_eu(1, 1)))
void rnn_scan_mfma(
    const float* __restrict__ W_rec,        // [128,128]
    const unsigned int* __restrict__ dpre,  // [B*T*64]
    float* __restrict__ states,             // [B,T,128]
    const float* __restrict__ alpha,        // [1]
    int T)
{
    const int bg    = blockIdx.x;
    const int chunk = blockIdx.y;
    const int lane  = threadIdx.x;
    const int col   = lane & 31;
    const int hi    = lane >> 5;
    const int b     = bg * 32 + col;

    const int NS   = T - 1;
    const int S    = (NS + NCHB - 1) / NCHB;
    const int s0   = chunk * S;
    if (s0 >= NS) return;
    const int e0   = min(NS, s0 + S);
    const int ws   = max(0, s0 - WARM);
    const int NSm1 = NS - 1;

    f16x8 Wf[4][8];
#pragma unroll
    for (int mt = 0; mt < 4; ++mt) {
        const float* wrow = W_rec + (size_t)(32 * mt + col) * NH + 8 * hi;
#pragma unroll
        for (int kk = 0; kk < 8; ++kk) {
            const float4* q = reinterpret_cast<const float4*>(wrow + 16 * kk);
            float4 f0 = q[0], f1 = q[1];
            vu4 uw = {pkh(f0.x, f0.y), pkh(f0.z, f0.w),
                      pkh(f1.x, f1.y), pkh(f1.z, f1.w)};
            Wf[mt][kk] = __builtin_bit_cast(f16x8, uw);
        }
    }
    asm volatile("" : "+a"(Wf[0][0]), "+a"(Wf[0][1]), "+a"(Wf[0][2]), "+a"(Wf[0][3]),
                      "+a"(Wf[0][4]), "+a"(Wf[0][5]), "+a"(Wf[0][6]), "+a"(Wf[0][7]),
                      "+a"(Wf[1][0]), "+a"(Wf[1][1]), "+a"(Wf[1][2]), "+a"(Wf[1][3]),
                      "+a"(Wf[1][4]), "+a"(Wf[1][5]), "+a"(Wf[1][6]), "+a"(Wf[1][7]));
    asm volatile("" : "+a"(Wf[2][0]), "+a"(Wf[2][1]), "+a"(Wf[2][2]), "+a"(Wf[2][3]),
                      "+a"(Wf[2][4]), "+a"(Wf[2][5]), "+a"(Wf[2][6]), "+a"(Wf[2][7]),
                      "+a"(Wf[3][0]), "+a"(Wf[3][1]), "+a"(Wf[3][2]), "+a"(Wf[3][3]),
                      "+a"(Wf[3][4]), "+a"(Wf[3][5]), "+a"(Wf[3][6]), "+a"(Wf[3][7]));

    const float av  = alpha[0];
    const float oma = 1.0f - av;
    f32x16 omv, avv, z16;
#pragma unroll
    for (int i = 0; i < 16; ++i) { omv[i] = oma; avv[i] = av; z16[i] = 0.f; }

    const unsigned int* dp_b = dpre + (size_t)b * T * 64;
    float* st_b = states + (size_t)b * T * NH;

    f32x16 xsv[4];
#pragma unroll
    for (int mt = 0; mt < 4; ++mt) xsv[mt] = z16;
    unsigned Bfd[8][4];
#pragma unroll
    for (int kk = 0; kk < 8; ++kk)
#pragma unroll
        for (int j = 0; j < 4; ++j) Bfd[kk][j] = 0u;

    if (chunk == 0) {
        float4 z4 = make_float4(0.f, 0.f, 0.f, 0.f);
#pragma unroll
        for (int mt = 0; mt < 4; ++mt)
#pragma unroll
            for (int g = 0; g < 4; ++g)
                *reinterpret_cast<float4*>(st_b + 32 * mt + 8 * g + 4 * hi) = z4;
    }

    uint2 dA[16];
#define LDDM(BUF, tt) { \
    const unsigned int* rp_ = dp_b + (size_t)(tt) * 64 + 2 * hi; \
    _Pragma("unroll") \
    for (int mt_ = 0; mt_ < 4; ++mt_) { \
        _Pragma("unroll") \
        for (int g_ = 0; g_ < 4; ++g_) \
            BUF[mt_ * 4 + g_] = \
                *reinterpret_cast<const uint2*>(rp_ + mt_ * 16 + g_ * 4); \
    } }

    LDDM(dA, ws)

#define STEPM(tt) { \
    f32x16 C[4]; \
    _Pragma("unroll") \
    for (int mt_ = 0; mt_ < 4; ++mt_) { \
        _Pragma("unroll") \
        for (int g_ = 0; g_ < 4; ++g_) { \
            uint2 dw_ = dA[mt_ * 4 + g_]; \
            h2v dl_ = H2(dw_.x), dh_ = H2(dw_.y); \
            C[mt_][4 * g_ + 0] = (float)dl_.x; \
            C[mt_][4 * g_ + 1] = (float)dl_.y; \
            C[mt_][4 * g_ + 2] = (float)dh_.x; \
            C[mt_][4 * g_ + 3] = (float)dh_.y; \
        } \
    } \
    LDDM(dA, min((tt) + 1, NSm1)) \
    _Pragma("unroll") \
    for (int kk_ = 0; kk_ < 8; ++kk_) { \
        vu4 bu_ = {Bfd[kk_][0], Bfd[kk_][1], Bfd[kk_][2], Bfd[kk_][3]}; \
        f16x8 bb_ = __builtin_bit_cast(f16x8, bu_); \
        _Pragma("unroll") \
        for (int mt_ = 0; mt_ < 4; ++mt_) \
            C[mt_] = __builtin_amdgcn_mfma_f32_32x32x16_f16( \
                Wf[mt_][kk_], bb_, C[mt_], 0, 0, 0); \
    } \
    _Pragma("unroll") \
    for (int mt_ = 0; mt_ < 4; ++mt_) { \
        f32x16 r_ = __builtin_elementwise_max(C[mt_], z16); \
        xsv[mt_] = __builtin_elementwise_fma(omv, xsv[mt_], avv * r_); \
    } \
    if ((tt) >= s0) { \
        float* row_ = st_b + (size_t)((tt) + 1) * NH + 4 * hi; \
        _Pragma("unroll") \
        for (int mt_ = 0; mt_ < 4; ++mt_) { \
            _Pragma("unroll") \
            for (int g_ = 0; g_ < 4; ++g_) \
                *reinterpret_cast<float4*>(row_ + 32 * mt_ + 8 * g_) = \
                    make_float4(xsv[mt_][g_ * 4 + 0], \
                                xsv[mt_][g_ * 4 + 1], \
                                xsv[mt_][g_ * 4 + 2], \
                                xsv[mt_][g_ * 4 + 3]); \
        } \
    } \
    unsigned P_[32]; \
    _Pragma("unroll") \
    for (int i_ = 0; i_ < 32; ++i_) \
        P_[i_] = pkh(xsv[i_ >> 3][(2 * i_) & 15], xsv[i_ >> 3][(2 * i_ + 1) & 15]); \
    _Pragma("unroll") \
    for (int mt_ = 0; mt_ < 4; ++mt_) { \
        _Pragma("unroll") \
        for (int gp_ = 0; gp_ < 2; ++gp_) { \
            _Pragma("unroll") \
            for (int r_ = 0; r_ < 2; ++r_) { \
                unsigned u_ = P_[mt_ * 8 + 4 * gp_ + r_]; \
                unsigned v_ = P_[mt_ * 8 + 4 * gp_ + 2 + r_]; \
                unsigned m_ = hi ? u_ : v_; \
                unsigned sm_ = (unsigned)__shfl_xor((int)m_, 32); \
                Bfd[2 * mt_ + gp_][r_]     = hi ? sm_ : u_; \
                Bfd[2 * mt_ + gp_][2 + r_] = hi ? v_  : sm_; \
            } \
        } \
    } }

#pragma unroll 1
    for (int t = ws; t < e0; ++t) {
        STEPM(t)
    }
#undef STEPM
#undef LDDM
}

// ---------------------------------------------------------------------------
// Fallback scan (R12 verbatim, exact, non-chunked): if ws_size too small.
// ---------------------------------------------------------------------------
__global__ __attribute__((amdgpu_flat_work_group_size(64, 64),
                          amdgpu_waves_per_eu(1, 1)))
void rnn_scan_fb(
    const float* __restrict__ u, const float* __restrict__ p,
    const float* __restrict__ alpha, const float* __restrict__ noise,
    const float* __restrict__ W_rec, const float* __restrict__ W_in,
    float* __restrict__ states, int T)
{
    const int b    = blockIdx.x;
    const int lane = threadIdx.x;
    const int n0   = lane * 2;

    __shared__ unsigned int xsh[64];

    const float* wr0 = W_rec + (size_t)n0 * NH;
    const float* wr1 = wr0 + NH;
    LDW(0)  LDW(1)  LDW(2)  LDW(3)  LDW(4)  LDW(5)  LDW(6)  LDW(7)
    LDW(8)  LDW(9)  LDW(10) LDW(11) LDW(12) LDW(13) LDW(14) LDW(15)
    PIN_AB();

    const float wiA0 = W_in[n0 * NI + 0], wiA1 = W_in[n0 * NI + 1];
    const float wiA2 = W_in[n0 * NI + 2], wiA3 = W_in[n0 * NI + 3];
    const float wiA4 = W_in[n0 * NI + 4], wiA5 = W_in[n0 * NI + 5];
    const float wiB0 = W_in[(n0 + 1) * NI + 0], wiB1 = W_in[(n0 + 1) * NI + 1];
    const float wiB2 = W_in[(n0 + 1) * NI + 2], wiB3 = W_in[(n0 + 1) * NI + 3];
    const float wiB4 = W_in[(n0 + 1) * NI + 4], wiB5 = W_in[(n0 + 1) * NI + 5];

    const float2 pn   = *reinterpret_cast<const float2*>(p + (size_t)b * NH + n0);
    const float av    = alpha[0];
    const float oma   = 1.0f - av;
    const float scale = sqrtf(2.0f * av * SIGMA_REC * SIGMA_REC);

    const float* noise_b = noise + (size_t)b * T * NH + n0;
    unsigned int zv;
    asm volatile("v_mov_b32 %0, 0" : "=v"(zv));
    const float* u_b = u + (size_t)b * T * NI + zv;
    float* st_ptr = states + (size_t)b * T * NH + n0 + NH;

    xsh[lane] = 0u;
    *reinterpret_cast<float2*>(states + (size_t)b * T * NH + n0) = make_float2(0.f, 0.f);
    float xo0 = 0.0f, xo1 = 0.0f;

    auto LDnz = [&](int t) {
        return *reinterpret_cast<const float2*>(noise_b + (size_t)t * NH);
    };
    auto loadU = [&](int t) {
        const float2* up = reinterpret_cast<const float2*>(u_b + (size_t)t * NI);
        U6 r; r.a = up[0]; r.b = up[1]; r.c = up[2]; return r;
    };
    auto mkd = [&](float2 nz, const U6& uu) {
        float dx = fmaf(uu.a.x, wiA0, fmaf(uu.a.y, wiA1, fmaf(uu.b.x, wiA2,
                   fmaf(uu.b.y, wiA3, fmaf(uu.c.x, wiA4, fmaf(uu.c.y, wiA5,
                   fmaf(scale, nz.x, pn.x)))))));
        float dy = fmaf(uu.a.x, wiB0, fmaf(uu.a.y, wiB1, fmaf(uu.b.x, wiB2,
                   fmaf(uu.b.y, wiB3, fmaf(uu.c.x, wiB4, fmaf(uu.c.y, wiB5,
                   fmaf(scale, nz.y, pn.y)))))));
        return make_float2(dx, dy);
    };
    auto step = [&](float2 d) {
        const vu4* xr = reinterpret_cast<const vu4*>(xsh);
        float c00 = 0.f, c01 = 0.f, c02 = 0.f, c03 = 0.f;
        float c10 = 0.f, c11 = 0.f, c12 = 0.f, c13 = 0.f;
        vu4 xv0 = xr[0], xv1 = xr[1], xv2 = xr[2], xv3 = xr[3];
        vu4 xv4 = xr[4], xv5 = xr[5], xv6 = xr[6], xv7 = xr[7];
        DOT_OCT(0, xv0);  DOT_OCT(1, xv1);  DOT_OCT(2, xv2);  DOT_OCT(3, xv3);
        vu4 xv8 = xr[8], xv9 = xr[9], xv10 = xr[10], xv11 = xr[11];
        DOT_OCT(4, xv4);  DOT_OCT(5, xv5);  DOT_OCT(6, xv6);  DOT_OCT(7, xv7);
        vu4 xv12 = xr[12], xv13 = xr[13], xv14 = xr[14], xv15 = xr[15];
        DOT_OCT(8, xv8);  DOT_OCT(9, xv9);  DOT_OCT(10, xv10); DOT_OCT(11, xv11);
        DOT_OCT(12, xv12); DOT_OCT(13, xv13); DOT_OCT(14, xv14); DOT_OCT(15, xv15);
        float pre0 = ((c00 + c01) + (c02 + c03)) + d.x;
        float pre1 = ((c10 + c11) + (c12 + c13)) + d.y;
        float xn0 = fmaf(oma, xo0, av * fmaxf(pre0, 0.f));
        float xn1 = fmaf(oma, xo1, av * fmaxf(pre1, 0.f));
        xo0 = xn0; xo1 = xn1;
        *reinterpret_cast<float2*>(st_ptr) = make_float2(xn0, xn1);
        st_ptr += NH;
        xsh[lane] = pkh(xn0, xn1);
    };

    float2 nz0 = LDnz(0), nz1 = LDnz(1), nz2 = LDnz(2), nz3 = LDnz(3);
    U6 u0 = loadU(0), u1 = loadU(1), u2 = loadU(2), u3 = loadU(3);
    float2 nzA0 = LDnz(4), nzA1 = LDnz(5);   U6 uA0 = loadU(4), uA1 = loadU(5);
    float2 nzB0 = LDnz(6), nzB1 = LDnz(7);   U6 uB0 = loadU(6), uB1 = loadU(7);
    float2 d0 = mkd(nz0, u0), d1 = mkd(nz1, u1);
    float2 d2 = mkd(nz2, u2), d3 = mkd(nz3, u3);

    int t = 0;
    for (; t + 1 < T - 1; t += 2) {
        const int t8 = min(t + 8, T - 1), t9 = min(t + 9, T - 1);
        float2 nzC0 = LDnz(t8), nzC1 = LDnz(t9);
        U6 uC0 = loadU(t8), uC1 = loadU(t9);
        float2 dE = mkd(nzA0, uA0), dF = mkd(nzA1, uA1);
        step(d0);
        step(d1);
        d0 = d2; d1 = d3; d2 = dE; d3 = dF;
        nzA0 = nzB0; nzA1 = nzB1; uA0 = uB0; uA1 = uB1;
        nzB0 = nzC0; nzB1 = nzC1; uB0 = uC0; uB1 = uC1;
    }
    if (t < T - 1) step(d0);
}

// ---------------------------------------------------------------------------
// Projection: out[r,o] = sum_n relu(states[r,n]) * W_out[o,n]
// ---------------------------------------------------------------------------
__global__ __launch_bounds__(256) void out_proj_kernel(
    const float* __restrict__ states,  // [rows,128]
    const float* __restrict__ W_out,   // [2,128]
    float* __restrict__ out,           // [rows,2]
    int rows)
{
    const int wave = threadIdx.x >> 6;
    const int lane = threadIdx.x & 63;
    const int l    = lane & 31;
    const int row  = blockIdx.x * 8 + wave * 2 + (lane >> 5);
    if (row >= rows) return;

    float4 s = *reinterpret_cast<const float4*>(states + (size_t)row * NH + l * 4);
    s.x = fmaxf(s.x, 0.f); s.y = fmaxf(s.y, 0.f);
    s.z = fmaxf(s.z, 0.f); s.w = fmaxf(s.w, 0.f);
    float4 wa = reinterpret_cast<const float4*>(W_out)[l];
    float4 wb = reinterpret_cast<const float4*>(W_out + NH)[l];
    float c0 = s.x * wa.x + s.y * wa.y + s.z * wa.z + s.w * wa.w;
    float c1 = s.x * wb.x + s.y * wb.y + s.z * wb.z + s.w * wb.w;

#pragma unroll
    for (int off = 16; off >= 1; off >>= 1) {
        c0 += __shfl_xor(c0, off);
        c1 += __shfl_xor(c1, off);
    }
    if (l == 0) {
        *reinterpret_cast<float2*>(out + (size_t)row * 2) = make_float2(c0, c1);
    }
}

// ---------------------------------------------------------------------------
extern "C" void kernel_launch(void* const* d_in, const int* in_sizes, int n_in,
                              void* d_out, int out_size, void* d_ws, size_t ws_size,
                              hipStream_t stream) {
    const float* u     = (const float*)d_in[0];
    const float* p     = (const float*)d_in[1];
    const float* alpha = (const float*)d_in[2];
    const float* noise = (const float*)d_in[3];
    const float* W_rec = (const float*)d_in[4];
    const float* W_in  = (const float*)d_in[5];
    const float* W_out = (const float*)d_in[6];

    const int B = in_sizes[1] / NH;           // 128
    const int T = in_sizes[0] / (B * NI);     // 3000

    float* out    = (float*)d_out;                    // [B,T,2]
    float* states = out + (size_t)B * T * 2;          // [B,T,128]

    const size_t need1 = (size_t)B * T * 64 * sizeof(unsigned int);  // 98.3 MB
    if (d_ws != nullptr && ws_size >= 2 * need1 && (B % 32) == 0) {
        // full path: drive -> transpose -> producer/consumer MFMA scan
        unsigned int* dpre  = (unsigned int*)d_ws;
        unsigned int* dpre2 = (unsigned int*)((char*)d_ws + need1);
        drive_kernel<<<2048, 256, 0, stream>>>(u, p, alpha, noise, W_in,
                                               dpre, B, T);
        dim3 tgrid((T + TILE_T - 1) / TILE_T, B / 32);
        transpose_d<<<tgrid, 256, 0, stream>>>(dpre, dpre2, T);
        dim3 grid(B / 32, NCHB);
        rnn_scan_mfma_pc<<<grid, 256, 0, stream>>>(W_rec, dpre2, states,
                                                   alpha, T);
    } else if (d_ws != nullptr && ws_size >= need1 && (B % 32) == 0) {
        unsigned int* dpre = (unsigned int*)d_ws;
        drive_kernel<<<2048, 256, 0, stream>>>(u, p, alpha, noise, W_in,
                                               dpre, B, T);
        dim3 grid(B / 32, NCHB);
        rnn_scan_mfma<<<grid, 64, 0, stream>>>(W_rec, dpre, states, alpha, T);
    } else {
        rnn_scan_fb<<<B, 64, 0, stream>>>(u, p, alpha, noise, W_rec, W_in,
                                          states, T);
    }

    const int rows = B * T;
    out_proj_kernel<<<(rows + 7) / 8, 256, 0, stream>>>(states, W_out, out, rows);
}

// Round 6
// 626.828 us; speedup vs baseline: 1.5210x; 1.3712x over previous
//
#include <hip/hip_runtime.h>
#include <math.h>

#define NH 128          // hidden size
#define NI 6            // input size
#define SIGMA_REC 0.15f
#define NCHUNK 8        // speculative chunks per batch row (R17-proven optimum:
                        // 4 waves/CU = 1 wave/SIMD, no VALU contention)
#define WARM 384        // warmup steps (R16/R17: absmax at 384 == f16 floor)

typedef __fp16 h2v __attribute__((ext_vector_type(2)));
typedef unsigned int vu4 __attribute__((ext_vector_type(4)));

__device__ __forceinline__ unsigned int pkh(float a, float b) {
    h2v h = __builtin_amdgcn_cvt_pkrtz(a, b);   // pack 2 f32 -> 2 f16 (RTZ)
    return __builtin_bit_cast(unsigned int, h);
}
#define H2(u) __builtin_bit_cast(h2v, (unsigned int)(u))

struct U6 { float2 a, b, c; };

// ---- load+pack one row's k-half of W: row n0+r, k in [64h, 64h+64) ----
#define LDWH(r) vu4 w##r##_0, w##r##_1, w##r##_2, w##r##_3, \
                    w##r##_4, w##r##_5, w##r##_6, w##r##_7; { \
    const float4* qp = reinterpret_cast<const float4*>( \
        W_rec + (size_t)(n0 + (r)) * NH + 64 * h); \
    float4 f0 = qp[0],  f1 = qp[1],  f2 = qp[2],  f3 = qp[3]; \
    float4 f4 = qp[4],  f5 = qp[5],  f6 = qp[6],  f7 = qp[7]; \
    float4 f8 = qp[8],  f9 = qp[9],  fA = qp[10], fB = qp[11]; \
    float4 fC = qp[12], fD = qp[13], fE = qp[14], fF = qp[15]; \
    w##r##_0 = (vu4){pkh(f0.x,f0.y), pkh(f0.z,f0.w), pkh(f1.x,f1.y), pkh(f1.z,f1.w)}; \
    w##r##_1 = (vu4){pkh(f2.x,f2.y), pkh(f2.z,f2.w), pkh(f3.x,f3.y), pkh(f3.z,f3.w)}; \
    w##r##_2 = (vu4){pkh(f4.x,f4.y), pkh(f4.z,f4.w), pkh(f5.x,f5.y), pkh(f5.z,f5.w)}; \
    w##r##_3 = (vu4){pkh(f6.x,f6.y), pkh(f6.z,f6.w), pkh(f7.x,f7.y), pkh(f7.z,f7.w)}; \
    w##r##_4 = (vu4){pkh(f8.x,f8.y), pkh(f8.z,f8.w), pkh(f9.x,f9.y), pkh(f9.z,f9.w)}; \
    w##r##_5 = (vu4){pkh(fA.x,fA.y), pkh(fA.z,fA.w), pkh(fB.x,fB.y), pkh(fB.z,fB.w)}; \
    w##r##_6 = (vu4){pkh(fC.x,fC.y), pkh(fC.z,fC.w), pkh(fD.x,fD.y), pkh(fD.z,fD.w)}; \
    w##r##_7 = (vu4){pkh(fE.x,fE.y), pkh(fE.z,fE.w), pkh(fF.x,fF.y), pkh(fF.z,fF.w)}; }

// ---- 32 pk_fma (2 chains of 16): row r's partial dot over this k-half ----
#define ROWDOT(r) h2v acc##r; { \
    h2v t0 = __builtin_elementwise_fma(H2(w##r##_0.x), H2(xh0.x), z2); \
    h2v t1 = __builtin_elementwise_fma(H2(w##r##_0.y), H2(xh0.y), z2); \
    t0 = __builtin_elementwise_fma(H2(w##r##_0.z), H2(xh0.z), t0); \
    t1 = __builtin_elementwise_fma(H2(w##r##_0.w), H2(xh0.w), t1); \
    t0 = __builtin_elementwise_fma(H2(w##r##_1.x), H2(xh1.x), t0); \
    t1 = __builtin_elementwise_fma(H2(w##r##_1.y), H2(xh1.y), t1); \
    t0 = __builtin_elementwise_fma(H2(w##r##_1.z), H2(xh1.z), t0); \
    t1 = __builtin_elementwise_fma(H2(w##r##_1.w), H2(xh1.w), t1); \
    t0 = __builtin_elementwise_fma(H2(w##r##_2.x), H2(xh2.x), t0); \
    t1 = __builtin_elementwise_fma(H2(w##r##_2.y), H2(xh2.y), t1); \
    t0 = __builtin_elementwise_fma(H2(w##r##_2.z), H2(xh2.z), t0); \
    t1 = __builtin_elementwise_fma(H2(w##r##_2.w), H2(xh2.w), t1); \
    t0 = __builtin_elementwise_fma(H2(w##r##_3.x), H2(xh3.x), t0); \
    t1 = __builtin_elementwise_fma(H2(w##r##_3.y), H2(xh3.y), t1); \
    t0 = __builtin_elementwise_fma(H2(w##r##_3.z), H2(xh3.z), t0); \
    t1 = __builtin_elementwise_fma(H2(w##r##_3.w), H2(xh3.w), t1); \
    t0 = __builtin_elementwise_fma(H2(w##r##_4.x), H2(xh4.x), t0); \
    t1 = __builtin_elementwise_fma(H2(w##r##_4.y), H2(xh4.y), t1); \
    t0 = __builtin_elementwise_fma(H2(w##r##_4.z), H2(xh4.z), t0); \
    t1 = __builtin_elementwise_fma(H2(w##r##_4.w), H2(xh4.w), t1); \
    t0 = __builtin_elementwise_fma(H2(w##r##_5.x), H2(xh5.x), t0); \
    t1 = __builtin_elementwise_fma(H2(w##r##_5.y), H2(xh5.y), t1); \
    t0 = __builtin_elementwise_fma(H2(w##r##_5.z), H2(xh5.z), t0); \
    t1 = __builtin_elementwise_fma(H2(w##r##_5.w), H2(xh5.w), t1); \
    t0 = __builtin_elementwise_fma(H2(w##r##_6.x), H2(xh6.x), t0); \
    t1 = __builtin_elementwise_fma(H2(w##r##_6.y), H2(xh6.y), t1); \
    t0 = __builtin_elementwise_fma(H2(w##r##_6.z), H2(xh6.z), t0); \
    t1 = __builtin_elementwise_fma(H2(w##r##_6.w), H2(xh6.w), t1); \
    t0 = __builtin_elementwise_fma(H2(w##r##_7.x), H2(xh7.x), t0); \
    t1 = __builtin_elementwise_fma(H2(w##r##_7.y), H2(xh7.y), t1); \
    t0 = __builtin_elementwise_fma(H2(w##r##_7.z), H2(xh7.z), t0); \
    t1 = __builtin_elementwise_fma(H2(w##r##_7.w), H2(xh7.w), t1); \
    acc##r = t0 + t1; }

// fallback-kernel helpers (R12-proven)
#define DOT_OCT(j, xv) \
    c00 = __builtin_amdgcn_fdot2(H2(a##j.x), H2((xv).x), c00, false); \
    c01 = __builtin_amdgcn_fdot2(H2(a##j.y), H2((xv).y), c01, false); \
    c02 = __builtin_amdgcn_fdot2(H2(a##j.z), H2((xv).z), c02, false); \
    c03 = __builtin_amdgcn_fdot2(H2(a##j.w), H2((xv).w), c03, false); \
    c10 = __builtin_amdgcn_fdot2(H2(b##j.x), H2((xv).x), c10, false); \
    c11 = __builtin_amdgcn_fdot2(H2(b##j.y), H2((xv).y), c11, false); \
    c12 = __builtin_amdgcn_fdot2(H2(b##j.z), H2((xv).z), c12, false); \
    c13 = __builtin_amdgcn_fdot2(H2(b##j.w), H2((xv).w), c13, false)

#define LDW(j) vu4 a##j, b##j; { \
    const float4* q0 = reinterpret_cast<const float4*>(wr0 + 8 * (j)); \
    const float4* q1 = reinterpret_cast<const float4*>(wr1 + 8 * (j)); \
    float4 f0 = q0[0], f1 = q0[1], g0 = q1[0], g1 = q1[1]; \
    a##j = (vu4){pkh(f0.x, f0.y), pkh(f0.z, f0.w), pkh(f1.x, f1.y), pkh(f1.z, f1.w)}; \
    b##j = (vu4){pkh(g0.x, g0.y), pkh(g0.z, g0.w), pkh(g1.x, g1.y), pkh(g1.z, g1.w)}; }

#define PIN_AB() \
    asm volatile("" : "+v"(a0), "+v"(a1), "+v"(a2),  "+v"(a3), \
                      "+v"(a4), "+v"(a5), "+v"(a6),  "+v"(a7), \
                      "+v"(a8), "+v"(a9), "+v"(a10), "+v"(a11), \
                      "+v"(a12), "+v"(a13), "+v"(a14), "+v"(a15)); \
    asm volatile("" : "+v"(b0), "+v"(b1), "+v"(b2),  "+v"(b3), \
                      "+v"(b4), "+v"(b5), "+v"(b6),  "+v"(b7), \
                      "+v"(b8), "+v"(b9), "+v"(b10), "+v"(b11), \
                      "+v"(b12), "+v"(b13), "+v"(b14), "+v"(b15))

// ---------------------------------------------------------------------------
// Kernel 0: precompute drive d[b,t,n] = u.W_in + scale*nz + p, packed f16.
// (R17-proven, unchanged.)
// ---------------------------------------------------------------------------
__global__ __launch_bounds__(256) void drive_kernel(
    const float* __restrict__ u,      // [B,T,6]
    const float* __restrict__ p,      // [B,128]
    const float* __restrict__ alpha,  // [1]
    const float* __restrict__ noise,  // [B,T,128]
    const float* __restrict__ W_in,   // [128,6]
    unsigned int* __restrict__ dpre,  // [B*T*64]
    int B, int T)
{
    const float av    = alpha[0];
    const float scale = sqrtf(2.0f * av * SIGMA_REC * SIGMA_REC);
    const size_t total = (size_t)B * T * 64;
    for (size_t idx = (size_t)blockIdx.x * 256 + threadIdx.x; idx < total;
         idx += (size_t)gridDim.x * 256) {
        const int    l  = (int)(idx & 63);
        const size_t bt = idx >> 6;
        const int    b  = (int)(bt / (unsigned)T);
        const int    t  = (int)(bt - (size_t)b * T);

        float2 nz = *reinterpret_cast<const float2*>(
            noise + ((size_t)b * T + t) * NH + 2 * l);
        const float2* ur = reinterpret_cast<const float2*>(
            u + ((size_t)b * T + t) * NI);
        float2 ua = ur[0], ub = ur[1], uc = ur[2];
        const float4* wv = reinterpret_cast<const float4*>(W_in + 2 * l * NI);
        float4 w0 = wv[0], w1 = wv[1], w2 = wv[2];   // rows 2l, 2l+1 (12 floats)
        float2 pv = *reinterpret_cast<const float2*>(p + (size_t)b * NH + 2 * l);

        float dx = fmaf(ua.x, w0.x, fmaf(ua.y, w0.y, fmaf(ub.x, w0.z,
                   fmaf(ub.y, w0.w, fmaf(uc.x, w1.x, fmaf(uc.y, w1.y,
                   fmaf(scale, nz.x, pv.x)))))));
        float dy = fmaf(ua.x, w1.z, fmaf(ua.y, w1.w, fmaf(ub.x, w2.x,
                   fmaf(ub.y, w2.y, fmaf(uc.x, w2.z, fmaf(uc.y, w2.w,
                   fmaf(scale, nz.y, pv.y)))))));
        dpre[idx] = pkh(dx, dy);
    }
}

// ---------------------------------------------------------------------------
// R23: the R17-proven chunked speculative scan (verbatim math), with the
// output projection FUSED into the commit epilogue. xn0..3 are live in
// registers at states-store time; out[b,t+1,:] = relu(x).W_out^T costs
// 4 fmax + 8 fma + 10 shfl + 1 lane-0 store on committed steps only
// (375 of 759) — and deletes out_proj's 196 MB re-read of states.
// (x >= 0 invariantly — relu kept for bit-safety, ~free.)
// ---------------------------------------------------------------------------
__global__ __attribute__((amdgpu_flat_work_group_size(64, 64),
                          amdgpu_waves_per_eu(1, 2)))
void rnn_scan_pre_f(
    const float* __restrict__ W_rec,  // [128,128]
    const unsigned int* __restrict__ dpre,  // [B*T*64]
    float* __restrict__ states,       // [B,T,128]
    float* __restrict__ out,          // [B,T,2]
    const float* __restrict__ W_out,  // [2,128]
    const float* __restrict__ alpha,  // [1]
    int T)
{
    const int b     = blockIdx.x;
    const int chunk = blockIdx.y;
    const int lane  = threadIdx.x;
    const int m     = lane & 31;
    const int h     = lane >> 5;      // k-half
    const int n0    = 4 * m;          // rows n0..n0+3

    const int NS   = T - 1;                       // 2999 steps total
    const int S    = (NS + NCHUNK - 1) / NCHUNK;  // 375
    const int s0   = chunk * S;
    const int e0   = min(NS, s0 + S);
    if (s0 >= NS) return;
    const int ws   = max(0, s0 - WARM);
    const int NSm1 = NS - 1;

    __shared__ unsigned int xsh[68];   // pairs: half0 @0-31, half1 @36-67

    // ---- W fragments: 4 rows x k-half, 32 named vu4 (128 dwords) ----
    LDWH(0) LDWH(1) LDWH(2) LDWH(3)
    asm volatile("" : "+v"(w0_0), "+v"(w0_1), "+v"(w0_2), "+v"(w0_3),
                      "+v"(w0_4), "+v"(w0_5), "+v"(w0_6), "+v"(w0_7),
                      "+v"(w1_0), "+v"(w1_1), "+v"(w1_2), "+v"(w1_3),
                      "+v"(w1_4), "+v"(w1_5), "+v"(w1_6), "+v"(w1_7));
    asm volatile("" : "+v"(w2_0), "+v"(w2_1), "+v"(w2_2), "+v"(w2_3),
                      "+v"(w2_4), "+v"(w2_5), "+v"(w2_6), "+v"(w2_7),
                      "+v"(w3_0), "+v"(w3_1), "+v"(w3_2), "+v"(w3_3),
                      "+v"(w3_4), "+v"(w3_5), "+v"(w3_6), "+v"(w3_7));

    const float av  = alpha[0];
    const float oma = 1.0f - av;

    // W_out rows for this lane's 4 n-values (same in both halves)
    const float4 wa = *reinterpret_cast<const float4*>(W_out + n0);
    const float4 wb = *reinterpret_cast<const float4*>(W_out + NH + n0);

    const unsigned int* d_b = dpre + (size_t)b * T * 64 + 2 * m;  // pairs 2m,2m+1
    float* states_b = states + (size_t)b * T * NH + n0;
    float* out_b    = out + (size_t)b * T * 2;

    // LDS write slot: h=0 writes pair 2m, h=1 writes pair 2m+1 (+4 pad if >=32)
    const int pidx  = 2 * m + h;
    const int wslot = pidx + ((pidx >= 32) ? 4 : 0);
    xsh[lane + ((lane >= 32) ? 4 : 0)] = 0u;    // zero all 64 data slots
    if (chunk == 0 && h == 0) {
        *reinterpret_cast<float4*>(states_b) = make_float4(0.f, 0.f, 0.f, 0.f);
        if (m == 0) *reinterpret_cast<float2*>(out_b) = make_float2(0.f, 0.f);
    }
    float xo0 = 0.f, xo1 = 0.f, xo2 = 0.f, xo3 = 0.f;

    auto LDD = [&](int t) {
        return *reinterpret_cast<const uint2*>(d_b + (size_t)t * 64);
    };
    const h2v z2 = {(__fp16)0.f, (__fp16)0.f};

    // d-prefetch ring, 8 deep
    uint2 dv0 = LDD(min(ws + 0, NSm1)), dv1 = LDD(min(ws + 1, NSm1));
    uint2 dv2 = LDD(min(ws + 2, NSm1)), dv3 = LDD(min(ws + 3, NSm1));
    uint2 dv4 = LDD(min(ws + 4, NSm1)), dv5 = LDD(min(ws + 5, NSm1));
    uint2 dv6 = LDD(min(ws + 6, NSm1)), dv7 = LDD(min(ws + 7, NSm1));

    for (int t = ws; t < e0; ++t) {
        uint2 dn = LDD(min(t + 8, NSm1));
        // ---- one step using dv0 ----
        const vu4* xr = reinterpret_cast<const vu4*>(xsh + h * 36);
        vu4 xh0 = xr[0], xh1 = xr[1], xh2 = xr[2], xh3 = xr[3];
        vu4 xh4 = xr[4], xh5 = xr[5], xh6 = xr[6], xh7 = xr[7];
        ROWDOT(0) ROWDOT(1) ROWDOT(2) ROWDOT(3)
        // partial sums -> f32, pack, exchange with other k-half (2 shfl)
        float f0 = (float)acc0.x + (float)acc0.y;
        float f1 = (float)acc1.x + (float)acc1.y;
        float f2 = (float)acc2.x + (float)acc2.y;
        float f3 = (float)acc3.x + (float)acc3.y;
        int pk01 = (int)pkh(f0, f1), pk23 = (int)pkh(f2, f3);
        h2v q01 = H2((unsigned)__shfl_xor(pk01, 32));
        h2v q23 = H2((unsigned)__shfl_xor(pk23, 32));
        float s0v = f0 + (float)q01.x, s1v = f1 + (float)q01.y;
        float s2v = f2 + (float)q23.x, s3v = f3 + (float)q23.y;
        // drive + blend
        h2v hd0 = H2(dv0.x), hd1 = H2(dv0.y);
        float xn0 = fmaf(oma, xo0, av * fmaxf(s0v + (float)hd0.x, 0.f));
        float xn1 = fmaf(oma, xo1, av * fmaxf(s1v + (float)hd0.y, 0.f));
        float xn2 = fmaf(oma, xo2, av * fmaxf(s2v + (float)hd1.x, 0.f));
        float xn3 = fmaf(oma, xo3, av * fmaxf(s3v + (float)hd1.y, 0.f));
        xo0 = xn0; xo1 = xn1; xo2 = xn2; xo3 = xn3;
        if (t >= s0) {
            if (h == 0) {
                *reinterpret_cast<float4*>(states_b + (size_t)(t + 1) * NH) =
                    make_float4(xn0, xn1, xn2, xn3);
            }
            // fused projection (all lanes; halves hold identical xn)
            float r0 = fmaxf(xn0, 0.f), r1 = fmaxf(xn1, 0.f);
            float r2 = fmaxf(xn2, 0.f), r3 = fmaxf(xn3, 0.f);
            float c0 = fmaf(r0, wa.x, fmaf(r1, wa.y, fmaf(r2, wa.z, r3 * wa.w)));
            float c1 = fmaf(r0, wb.x, fmaf(r1, wb.y, fmaf(r2, wb.z, r3 * wb.w)));
#pragma unroll
            for (int off = 16; off >= 1; off >>= 1) {
                c0 += __shfl_xor(c0, off);
                c1 += __shfl_xor(c1, off);
            }
            if (lane == 0) {
                *reinterpret_cast<float2*>(out_b + (size_t)(t + 1) * 2) =
                    make_float2(c0, c1);
            }
        }
        // each lane writes ONE pair dword (h selects even/odd pair)
        xsh[wslot] = h ? pkh(xn2, xn3) : pkh(xn0, xn1);
        // rotate ring
        dv0 = dv1; dv1 = dv2; dv2 = dv3; dv3 = dv4;
        dv4 = dv5; dv5 = dv6; dv6 = dv7; dv7 = dn;
    }
}

// ---------------------------------------------------------------------------
// Fallback scan (R12 verbatim, exact, non-chunked): if ws_size too small.
// ---------------------------------------------------------------------------
__global__ __attribute__((amdgpu_flat_work_group_size(64, 64),
                          amdgpu_waves_per_eu(1, 1)))
void rnn_scan_fb(
    const float* __restrict__ u, const float* __restrict__ p,
    const float* __restrict__ alpha, const float* __restrict__ noise,
    const float* __restrict__ W_rec, const float* __restrict__ W_in,
    float* __restrict__ states, int T)
{
    const int b    = blockIdx.x;
    const int lane = threadIdx.x;
    const int n0   = lane * 2;

    __shared__ unsigned int xsh[64];

    const float* wr0 = W_rec + (size_t)n0 * NH;
    const float* wr1 = wr0 + NH;
    LDW(0)  LDW(1)  LDW(2)  LDW(3)  LDW(4)  LDW(5)  LDW(6)  LDW(7)
    LDW(8)  LDW(9)  LDW(10) LDW(11) LDW(12) LDW(13) LDW(14) LDW(15)
    PIN_AB();

    const float wiA0 = W_in[n0 * NI + 0], wiA1 = W_in[n0 * NI + 1];
    const float wiA2 = W_in[n0 * NI + 2], wiA3 = W_in[n0 * NI + 3];
    const float wiA4 = W_in[n0 * NI + 4], wiA5 = W_in[n0 * NI + 5];
    const float wiB0 = W_in[(n0 + 1) * NI + 0], wiB1 = W_in[(n0 + 1) * NI + 1];
    const float wiB2 = W_in[(n0 + 1) * NI + 2], wiB3 = W_in[(n0 + 1) * NI + 3];
    const float wiB4 = W_in[(n0 + 1) * NI + 4], wiB5 = W_in[(n0 + 1) * NI + 5];

    const float2 pn   = *reinterpret_cast<const float2*>(p + (size_t)b * NH + n0);
    const float av    = alpha[0];
    const float oma   = 1.0f - av;
    const float scale = sqrtf(2.0f * av * SIGMA_REC * SIGMA_REC);

    const float* noise_b = noise + (size_t)b * T * NH + n0;
    unsigned int zv;
    asm volatile("v_mov_b32 %0, 0" : "=v"(zv));
    const float* u_b = u + (size_t)b * T * NI + zv;
    float* st_ptr = states + (size_t)b * T * NH + n0 + NH;

    xsh[lane] = 0u;
    *reinterpret_cast<float2*>(states + (size_t)b * T * NH + n0) = make_float2(0.f, 0.f);
    float xo0 = 0.0f, xo1 = 0.0f;

    auto LDnz = [&](int t) {
        return *reinterpret_cast<const float2*>(noise_b + (size_t)t * NH);
    };
    auto loadU = [&](int t) {
        const float2* up = reinterpret_cast<const float2*>(u_b + (size_t)t * NI);
        U6 r; r.a = up[0]; r.b = up[1]; r.c = up[2]; return r;
    };
    auto mkd = [&](float2 nz, const U6& uu) {
        float dx = fmaf(uu.a.x, wiA0, fmaf(uu.a.y, wiA1, fmaf(uu.b.x, wiA2,
                   fmaf(uu.b.y, wiA3, fmaf(uu.c.x, wiA4, fmaf(uu.c.y, wiA5,
                   fmaf(scale, nz.x, pn.x)))))));
        float dy = fmaf(uu.a.x, wiB0, fmaf(uu.a.y, wiB1, fmaf(uu.b.x, wiB2,
                   fmaf(uu.b.y, wiB3, fmaf(uu.c.x, wiB4, fmaf(uu.c.y, wiB5,
                   fmaf(scale, nz.y, pn.y)))))));
        return make_float2(dx, dy);
    };
    auto step = [&](float2 d) {
        const vu4* xr = reinterpret_cast<const vu4*>(xsh);
        float c00 = 0.f, c01 = 0.f, c02 = 0.f, c03 = 0.f;
        float c10 = 0.f, c11 = 0.f, c12 = 0.f, c13 = 0.f;
        vu4 xv0 = xr[0], xv1 = xr[1], xv2 = xr[2], xv3 = xr[3];
        vu4 xv4 = xr[4], xv5 = xr[5], xv6 = xr[6], xv7 = xr[7];
        DOT_OCT(0, xv0);  DOT_OCT(1, xv1);  DOT_OCT(2, xv2);  DOT_OCT(3, xv3);
        vu4 xv8 = xr[8], xv9 = xr[9], xv10 = xr[10], xv11 = xr[11];
        DOT_OCT(4, xv4);  DOT_OCT(5, xv5);  DOT_OCT(6, xv6);  DOT_OCT(7, xv7);
        vu4 xv12 = xr[12], xv13 = xr[13], xv14 = xr[14], xv15 = xr[15];
        DOT_OCT(8, xv8);  DOT_OCT(9, xv9);  DOT_OCT(10, xv10); DOT_OCT(11, xv11);
        DOT_OCT(12, xv12); DOT_OCT(13, xv13); DOT_OCT(14, xv14); DOT_OCT(15, xv15);
        float pre0 = ((c00 + c01) + (c02 + c03)) + d.x;
        float pre1 = ((c10 + c11) + (c12 + c13)) + d.y;
        float xn0 = fmaf(oma, xo0, av * fmaxf(pre0, 0.f));
        float xn1 = fmaf(oma, xo1, av * fmaxf(pre1, 0.f));
        xo0 = xn0; xo1 = xn1;
        *reinterpret_cast<float2*>(st_ptr) = make_float2(xn0, xn1);
        st_ptr += NH;
        xsh[lane] = pkh(xn0, xn1);
    };

    float2 nz0 = LDnz(0), nz1 = LDnz(1), nz2 = LDnz(2), nz3 = LDnz(3);
    U6 u0 = loadU(0), u1 = loadU(1), u2 = loadU(2), u3 = loadU(3);
    float2 nzA0 = LDnz(4), nzA1 = LDnz(5);   U6 uA0 = loadU(4), uA1 = loadU(5);
    float2 nzB0 = LDnz(6), nzB1 = LDnz(7);   U6 uB0 = loadU(6), uB1 = loadU(7);
    float2 d0 = mkd(nz0, u0), d1 = mkd(nz1, u1);
    float2 d2 = mkd(nz2, u2), d3 = mkd(nz3, u3);

    int t = 0;
    for (; t + 1 < T - 1; t += 2) {
        const int t8 = min(t + 8, T - 1), t9 = min(t + 9, T - 1);
        float2 nzC0 = LDnz(t8), nzC1 = LDnz(t9);
        U6 uC0 = loadU(t8), uC1 = loadU(t9);
        float2 dE = mkd(nzA0, uA0), dF = mkd(nzA1, uA1);
        step(d0);
        step(d1);
        d0 = d2; d1 = d3; d2 = dE; d3 = dF;
        nzA0 = nzB0; nzA1 = nzB1; uA0 = uB0; uA1 = uB1;
        nzB0 = nzC0; nzB1 = nzC1; uB0 = uC0; uB1 = uC1;
    }
    if (t < T - 1) step(d0);
}

// ---------------------------------------------------------------------------
// Projection (fallback path only): out[r,o] = sum_n relu(states[r,n]) * W_out[o,n]
// ---------------------------------------------------------------------------
__global__ __launch_bounds__(256) void out_proj_kernel(
    const float* __restrict__ states,  // [rows,128]
    const float* __restrict__ W_out,   // [2,128]
    float* __restrict__ out,           // [rows,2]
    int rows)
{
    const int wave = threadIdx.x >> 6;
    const int lane = threadIdx.x & 63;
    const int l    = lane & 31;
    const int row  = blockIdx.x * 8 + wave * 2 + (lane >> 5);
    if (row >= rows) return;

    float4 s = *reinterpret_cast<const float4*>(states + (size_t)row * NH + l * 4);
    s.x = fmaxf(s.x, 0.f); s.y = fmaxf(s.y, 0.f);
    s.z = fmaxf(s.z, 0.f); s.w = fmaxf(s.w, 0.f);
    float4 wa = reinterpret_cast<const float4*>(W_out)[l];
    float4 wb = reinterpret_cast<const float4*>(W_out + NH)[l];
    float c0 = s.x * wa.x + s.y * wa.y + s.z * wa.z + s.w * wa.w;
    float c1 = s.x * wb.x + s.y * wb.y + s.z * wb.z + s.w * wb.w;

#pragma unroll
    for (int off = 16; off >= 1; off >>= 1) {
        c0 += __shfl_xor(c0, off);
        c1 += __shfl_xor(c1, off);
    }
    if (l == 0) {
        *reinterpret_cast<float2*>(out + (size_t)row * 2) = make_float2(c0, c1);
    }
}

// ---------------------------------------------------------------------------
extern "C" void kernel_launch(void* const* d_in, const int* in_sizes, int n_in,
                              void* d_out, int out_size, void* d_ws, size_t ws_size,
                              hipStream_t stream) {
    const float* u     = (const float*)d_in[0];
    const float* p     = (const float*)d_in[1];
    const float* alpha = (const float*)d_in[2];
    const float* noise = (const float*)d_in[3];
    const float* W_rec = (const float*)d_in[4];
    const float* W_in  = (const float*)d_in[5];
    const float* W_out = (const float*)d_in[6];

    const int B = in_sizes[1] / NH;           // 128
    const int T = in_sizes[0] / (B * NI);     // 3000

    float* out    = (float*)d_out;                    // [B,T,2]
    float* states = out + (size_t)B * T * 2;          // [B,T,128]

    const size_t need = (size_t)B * T * 64 * sizeof(unsigned int);  // 98.3 MB
    if (d_ws != nullptr && ws_size >= need) {
        unsigned int* dpre = (unsigned int*)d_ws;
        drive_kernel<<<2048, 256, 0, stream>>>(u, p, alpha, noise, W_in,
                                               dpre, B, T);
        dim3 grid(B, NCHUNK);
        rnn_scan_pre_f<<<grid, 64, 0, stream>>>(W_rec, dpre, states, out,
                                                W_out, alpha, T);
    } else {
        rnn_scan_fb<<<B, 64, 0, stream>>>(u, p, alpha, noise, W_rec, W_in,
                                          states, T);
        const int rows = B * T;
        out_proj_kernel<<<(rows + 7) / 8, 256, 0, stream>>>(states, W_out,
                                                            out, rows);
    }
}